// Round 12
// baseline (376.338 us; speedup 1.0000x reference)
//
#include <hip/hip_runtime.h>
#include <hip/hip_bf16.h>

#define B_   4
#define CIN  64
#define HID  256
#define COUT 64
#define T_   16
#define H_   64
#define W_   64
#define HW_  (H_*W_)       // 4096
#define THW  (T_*HW_)      // 65536
#define EPS  1e-5f

typedef unsigned short ushort_t;
typedef unsigned int   uint_t;
typedef short bf16x8 __attribute__((ext_vector_type(8)));
typedef float f32x4  __attribute__((ext_vector_type(4)));

// ---- stats in static device memory -------------------------------------------
#define SM3   4096
#define SIS3  5120
#define SSES  6144
#define SAL   7168
#define SBE   8192
__device__ float g_stats[10240];
// per-(bb, pos-block, channel) partial sums from k_expand epilogue (stats1).
// layout [bb][posblk][ch]: k_expand's write (tid=ch) is COALESCED (the hot
// side); k_mid's read (tid=posblk, stride 256 floats) is strided but the 8 MB
// arrays are L2-resident and it's a one-shot block prologue. R11 proved the
// transposed layout costs ~25 us in write amplification.
__device__ float g_eps [4*1024*256];
__device__ float g_epss[4*1024*256];
// per-(bb, channel, pos-block) proj partial sums from k_proj epilogue
__device__ float g_pps [4*64*512];
__device__ float g_ppss[4*64*512];
// packed bf16 weights in MFMA fragment order: [0:16384) expand, [16384:32768) proj
__device__ ushort_t g_wpack[32768];

__device__ __forceinline__ float bf2f(ushort_t u) {
    return __uint_as_float(((uint_t)u) << 16);
}
__device__ __forceinline__ ushort_t f2bf(float f) {
    uint_t u = __float_as_uint(f);
    uint_t r = u + 0x7fffu + ((u >> 16) & 1u);   // round-to-nearest-even
    return (ushort_t)(r >> 16);
}
__device__ __forceinline__ void unpacknorm2(uint2 k, float a, float bb, float* v) {
    uint_t uu[2] = {k.x, k.y};
    #pragma unroll
    for (int j = 0; j < 2; ++j) {
        v[2*j]   = fmaxf(fmaf(__uint_as_float(uu[j] << 16),         a, bb), 0.f);
        v[2*j+1] = fmaxf(fmaf(__uint_as_float(uu[j] & 0xffff0000u), a, bb), 0.f);
    }
}

// ---- pack w1 + wproj into bf16 fragment order --------------------------------
__global__ __launch_bounds__(256) void k_prep(const float* __restrict__ w1,
                                              const float* __restrict__ wproj) {
    int idx = blockIdx.x*256 + threadIdx.x;        // 0..16383
    {
        int j = idx & 7, lane = (idx>>3) & 63, ot = (idx>>9) & 3;
        int ks = (idx>>11) & 1, wv = idx >> 12;
        int ln = lane & 15, q = lane >> 4;
        int o = wv*64 + ot*16 + ln, k = ks*32 + q*8 + j;
        g_wpack[idx] = f2bf(w1[o*CIN + k]);
    }
    {
        int j = idx & 7, lane = (idx>>3) & 63, ot = (idx>>9) & 3, kg = idx >> 11;
        int ln = lane & 15, q = lane >> 4;
        int o = ot*16 + ln, k = kg*32 + q*8 + j;
        g_wpack[16384 + idx] = f2bf(wproj[o*HID + k]);
    }
}

// ============ expand 1x1 via MFMA + fused per-channel stats1 partials =========
__global__ __launch_bounds__(256) void k_expand(const float* __restrict__ x,
                                                ushort_t* __restrict__ h1, int b0) {
    union SMem {
        ushort_t Bs[64*72];          // B[k][n], stride 72, rotated cols (18.4 KB)
        float    red[2][256][16];    // per-channel per-16lane partials (32 KB)
    };
    __shared__ SMem sm;
    const int tid = threadIdx.x;
    const int bb  = blockIdx.y, gb = b0 + bb;
    const int pos0 = blockIdx.x * 64;
    const int lane = tid & 63, wv = tid >> 6;
    const int q = lane >> 4, ln = lane & 15;

    bf16x8 af[2][4];
    #pragma unroll
    for (int ks = 0; ks < 2; ++ks)
        #pragma unroll
        for (int ot = 0; ot < 4; ++ot)
            af[ks][ot] = *(const bf16x8*)&g_wpack[(((wv*2+ks)*4+ot)<<9) + lane*8];

    #pragma unroll
    for (int i = 0; i < 4; ++i) {
        int lin = i*1024 + tid*4;
        int k = lin >> 6, n0 = lin & 63;
        float4 v = *(const float4*)&x[(size_t)(gb*CIN + k) * THW + pos0 + n0];
        ushort_t* d = &sm.Bs[k*72 + ((n0 + 16*((k>>3)&3)) & 63)];
        d[0] = f2bf(v.x); d[1] = f2bf(v.y); d[2] = f2bf(v.z); d[3] = f2bf(v.w);
    }
    __syncthreads();

    f32x4 acc[4][4];
    #pragma unroll
    for (int i = 0; i < 4; ++i)
        #pragma unroll
        for (int j = 0; j < 4; ++j)
            acc[i][j] = (f32x4){0.f,0.f,0.f,0.f};

    #pragma unroll
    for (int ks = 0; ks < 2; ++ks) {
        bf16x8 bfr[4];
        #pragma unroll
        for (int nt = 0; nt < 4; ++nt) {
            union { short s[8]; bf16x8 v; } bu;
            #pragma unroll
            for (int j = 0; j < 8; ++j) {
                int k = ks*32 + q*8 + j;
                int nn = (nt*16 + ln + 16*((k>>3)&3)) & 63;
                bu.s[j] = (short)sm.Bs[k*72 + nn];
            }
            bfr[nt] = bu.v;
        }
        #pragma unroll
        for (int ot = 0; ot < 4; ++ot)
            #pragma unroll
            for (int nt = 0; nt < 4; ++nt)
                acc[ot][nt] = __builtin_amdgcn_mfma_f32_16x16x32_bf16(
                    af[ks][ot], bfr[nt], acc[ot][nt], 0, 0, 0);
    }

    // epilogue: store + accumulate per-lane per-channel partial sums
    float sp_[16], ssp_[16];
    #pragma unroll
    for (int i = 0; i < 16; ++i) { sp_[i] = 0.f; ssp_[i] = 0.f; }

    #pragma unroll
    for (int ot = 0; ot < 4; ++ot)
        #pragma unroll
        for (int nt = 0; nt < 4; ++nt)
            #pragma unroll
            for (int r = 0; r < 4; ++r) {
                float vv = acc[ot][nt][r];
                int o = wv*64 + ot*16 + q*4 + r;
                int n = nt*16 + ln;
                h1[((size_t)bb*HID + o)*THW + pos0 + n] = f2bf(vv);
                sp_[ot*4+r] += vv;
                ssp_[ot*4+r] = fmaf(vv, vv, ssp_[ot*4+r]);
            }

    __syncthreads();           // all waves done reading Bs before union reuse
    #pragma unroll
    for (int i = 0; i < 16; ++i) {
        int o = wv*64 + (i>>2)*16 + q*4 + (i&3);
        sm.red[0][o][ln] = sp_[i];
        sm.red[1][o][ln] = ssp_[i];
    }
    __syncthreads();
    {
        float s = 0.f, ss = 0.f;
        #pragma unroll
        for (int l = 0; l < 16; ++l) {
            s  += sm.red[0][tid][l];
            ss += sm.red[1][tid][l];
        }
        size_t base = ((size_t)bb*1024 + blockIdx.x)*256 + tid;   // coalesced
        g_eps [base] = s;
        g_epss[base] = ss;
    }
}

// ===== fused stage2+stage3: spatial dw3x3 -> IN -> relu -> temporal dw3 =======
// one block (1024 thr) per (bb, channel); dws output in keep[16] uint2 registers.
// Halo-padded LDS plane removes all boundary branches; T14 reg-staging (load
// plane t+2 at iter t, LDS-write at t+1) hides the h1 read latency under a full
// conv phase. NO forced min-occupancy: R8 showed (1024,8) forces spill (VGPR 32,
// +310 MB scratch traffic); unforced allocator lands 48 VGPR, no spill (R11).
__global__ __launch_bounds__(1024) void k_mid(const ushort_t* __restrict__ h1,
                                              const float* __restrict__ wdws,
                                              const float* __restrict__ wdwt,
                                              ushort_t* __restrict__ h3) {
    const int tid = threadIdx.x;                  // 0..1023
    const int bc  = blockIdx.x;
    const int o   = bc & (HID-1);
    const int bb  = bc >> 8;
    const int wid = tid >> 6, lane = tid & 63;

    if (o >= 32 && o < 64) {                      // zero-forced TIM channels
        if (tid == 0) {
            g_stats[SM3  + bc] = 0.f;
            g_stats[SIS3 + bc] = 1.f / sqrtf(EPS);
            g_stats[SSES + bc] = 0.f;
        }
        return;
    }

    __shared__ float pl[2][66*67];                // halo-padded norm'd planes
    __shared__ float ls[16], lss[16];
    __shared__ float sa, sb;

    // ---- stats1 for this channel from k_expand partials (L2-hot read) -------
    {
        const float* ps  = &g_eps [((size_t)bb*1024)*256 + o];
        const float* pss = &g_epss[((size_t)bb*1024)*256 + o];
        float s  = ps [(size_t)tid*256];
        float ss = pss[(size_t)tid*256];
        #pragma unroll
        for (int m = 32; m > 0; m >>= 1) {
            s  += __shfl_xor(s,  m);
            ss += __shfl_xor(ss, m);
        }
        if (lane == 0) { ls[wid] = s; lss[wid] = ss; }
        // halo zero (both buffers) overlapped with the reduction
        if (tid < 66) {
            #pragma unroll
            for (int b = 0; b < 2; ++b) {
                pl[b][tid]         = 0.f;         // row 0
                pl[b][65*67 + tid] = 0.f;         // row 65
                pl[b][tid*67]      = 0.f;         // col 0
                pl[b][tid*67 + 65] = 0.f;         // col 65
            }
        }
        __syncthreads();
        if (tid == 0) {
            float st = 0.f, sst = 0.f;
            #pragma unroll
            for (int i = 0; i < 16; ++i) { st += ls[i]; sst += lss[i]; }
            float m = st * (1.f/THW);
            float v = sst * (1.f/THW) - m*m;
            float is = 1.f / sqrtf(v + EPS);
            sa = is; sb = -m * is;
        }
        __syncthreads();
    }
    const float a1 = sa, b1 = sb;

    const int fut = (o < 32) ? 1 : 0;             // TIM future-shifted channel
    const int y   = tid >> 4;                     // 0..63
    const int x0  = (tid & 15) * 4;               // 0..60
    const ushort_t* chp = h1 + (size_t)bc * THW;
    const int lastp = fut ? (T_-2) : (T_-1);      // last plane with real input

    float wf[9];
    #pragma unroll
    for (int k = 0; k < 9; ++k) wf[k] = wdws[o*9 + k];

    // prologue: plane 0 staged (latency exposed once), plane 1 load in flight
    uint2 sreg[2];
    sreg[0] = *(const uint2*)(chp + (size_t)fut*HW_ + tid*4);
    {
        float vv[4];
        unpacknorm2(sreg[0], a1, b1, vv);
        float* dst = &pl[0][(y+1)*67 + x0 + 1];
        #pragma unroll
        for (int i = 0; i < 4; ++i) dst[i] = vv[i];
    }
    sreg[1] = *(const uint2*)(chp + (size_t)(1+fut)*HW_ + tid*4);
    __syncthreads();

    // ---- phase A: spatial 3x3 conv, outputs kept in registers ----------------
    uint2 keep[16];
    float s2 = 0.f, ss2 = 0.f;

    #pragma unroll
    for (int t = 0; t < T_; ++t) {
        // issue raw load for plane t+2 (consumed next iteration)
        if (t + 2 <= lastp)
            sreg[t & 1] = *(const uint2*)(chp + (size_t)(t+2+fut)*HW_ + tid*4);
        // normalize + LDS-write plane t+1 (loaded one iteration ago)
        if (t + 1 <= lastp) {
            float vv[4];
            unpacknorm2(sreg[(t+1) & 1], a1, b1, vv);
            float* dst = &pl[(t+1) & 1][(y+1)*67 + x0 + 1];
            #pragma unroll
            for (int i = 0; i < 4; ++i) dst[i] = vv[i];
        }
        if (fut && t == T_-1) {
            keep[t] = (uint2){0u, 0u};            // TIM zero plane: dws out = 0
        } else {
            const float* plane = pl[t & 1];
            float v[3][6];
            #pragma unroll
            for (int dy = 0; dy < 3; ++dy) {
                const float* rp = &plane[(y + dy)*67 + x0];
                #pragma unroll
                for (int j = 0; j < 6; ++j) v[dy][j] = rp[j];
            }
            uint_t outp[2];
            #pragma unroll
            for (int i2 = 0; i2 < 2; ++i2) {
                float o0 = 0.f, o1 = 0.f;
                #pragma unroll
                for (int dy = 0; dy < 3; ++dy)
                    #pragma unroll
                    for (int dx = 0; dx < 3; ++dx) {
                        float w = wf[dy*3+dx];
                        o0 = fmaf(w, v[dy][2*i2 + dx],     o0);
                        o1 = fmaf(w, v[dy][2*i2 + 1 + dx], o1);
                    }
                ushort_t u0 = f2bf(o0), u1 = f2bf(o1);
                float r0 = bf2f(u0), r1 = bf2f(u1);
                s2 += r0 + r1; ss2 = fmaf(r0, r0, fmaf(r1, r1, ss2));
                outp[i2] = (uint_t)u0 | ((uint_t)u1 << 16);
            }
            keep[t].x = outp[0]; keep[t].y = outp[1];
        }
        __syncthreads();
    }

    // ---- phase B: stats2 block-reduce (never touches HBM) --------------------
    {
        float s = s2, ss = ss2;
        #pragma unroll
        for (int m = 32; m > 0; m >>= 1) {
            s  += __shfl_xor(s,  m);
            ss += __shfl_xor(ss, m);
        }
        if (lane == 0) { ls[wid] = s; lss[wid] = ss; }
        __syncthreads();
        if (tid == 0) {
            float st = 0.f, sst = 0.f;
            #pragma unroll
            for (int i = 0; i < 16; ++i) { st += ls[i]; sst += lss[i]; }
            float m = st * (1.f/THW);
            float v = sst * (1.f/THW) - m*m;
            float is = 1.f / sqrtf(v + EPS);
            sa = is; sb = -m * is;
        }
        __syncthreads();
    }
    const float a2 = sa, b2 = sb;
    // note: for fut channels keep[15]==0 -> unpacknorm2 gives relu(b2) == znorm

    // ---- phase C: temporal dw3 from registers, write h3, stats3 --------------
    const float w0 = wdwt[o*3+0], w1 = wdwt[o*3+1], w2 = wdwt[o*3+2];
    ushort_t* op = h3 + (size_t)bc * THW + tid*4;

    float p[4], c[4], n[4];
    #pragma unroll
    for (int i = 0; i < 4; ++i) p[i] = 0.f;
    unpacknorm2(keep[0], a2, b2, c);
    unpacknorm2(keep[1], a2, b2, n);

    float s3 = 0.f, ss3 = 0.f;
    #pragma unroll
    for (int t = 0; t < T_; ++t) {
        uint_t outp[2];
        #pragma unroll
        for (int i2 = 0; i2 < 2; ++i2) {
            float o0 = fmaf(w0, p[2*i2],   fmaf(w1, c[2*i2],   w2 * n[2*i2]));
            float o1 = fmaf(w0, p[2*i2+1], fmaf(w1, c[2*i2+1], w2 * n[2*i2+1]));
            ushort_t u0 = f2bf(o0), u1 = f2bf(o1);
            float r0 = bf2f(u0), r1 = bf2f(u1);
            s3 += r0 + r1; ss3 = fmaf(r0, r0, fmaf(r1, r1, ss3));
            outp[i2] = (uint_t)u0 | ((uint_t)u1 << 16);
        }
        uint2 r; r.x = outp[0]; r.y = outp[1];
        *(uint2*)(op + (size_t)t*HW_) = r;

        #pragma unroll
        for (int i = 0; i < 4; ++i) { p[i] = c[i]; c[i] = n[i]; }
        if (t + 2 < T_) unpacknorm2(keep[t+2], a2, b2, n);
        else {
            #pragma unroll
            for (int i = 0; i < 4; ++i) n[i] = 0.f;   // true conv zero-padding
        }
        keep[t] = r;                                   // reuse for SE-mean pass
    }

    {
        float s = s3, ss = ss3;
        #pragma unroll
        for (int m = 32; m > 0; m >>= 1) {
            s  += __shfl_xor(s,  m);
            ss += __shfl_xor(ss, m);
        }
        if (lane == 0) { ls[wid] = s; lss[wid] = ss; }
        __syncthreads();
        if (tid == 0) {
            float st = 0.f, sst = 0.f;
            #pragma unroll
            for (int i = 0; i < 16; ++i) { st += ls[i]; sst += lss[i]; }
            float m = st * (1.f/THW);
            float v = sst * (1.f/THW) - m*m;
            float is = 1.f / sqrtf(v + EPS);
            g_stats[SM3  + bc] = m;
            g_stats[SIS3 + bc] = is;
            sa = is; sb = -m * is;
        }
        __syncthreads();
    }

    // ---- phase D: SE mean of relu(norm3(h3)) from kept registers -------------
    const float a3 = sa, b3 = sb;
    float sse = 0.f;
    #pragma unroll
    for (int t = 0; t < T_; ++t) {
        uint_t uu[2] = {keep[t].x, keep[t].y};
        #pragma unroll
        for (int j = 0; j < 2; ++j) {
            sse += fmaxf(fmaf(__uint_as_float(uu[j] << 16),         a3, b3), 0.f);
            sse += fmaxf(fmaf(__uint_as_float(uu[j] & 0xffff0000u), a3, b3), 0.f);
        }
    }
    #pragma unroll
    for (int m = 32; m > 0; m >>= 1) sse += __shfl_xor(sse, m);
    if (lane == 0) ls[wid] = sse;
    __syncthreads();
    if (tid == 0) {
        float st = 0.f;
        #pragma unroll
        for (int i = 0; i < 16; ++i) st += ls[i];
        g_stats[SSES + bc] = st * (1.f/THW);
    }
}

// ------------ SE MLP -> fold sigmoid scale into proj's alpha/beta -------------
__global__ __launch_bounds__(256) void k_semlp(const float* __restrict__ wse1,
                                               const float* __restrict__ wse2) {
    __shared__ float mv[HID];
    __shared__ float y1[64];
    const int bb = blockIdx.x, tid = threadIdx.x;
    mv[tid] = g_stats[SSES + bb*HID + tid];
    __syncthreads();
    if (tid < 64) {
        float acc = 0.f;
        #pragma unroll 8
        for (int c = 0; c < HID; ++c) acc = fmaf(wse1[tid*HID + c], mv[c], acc);
        y1[tid] = fmaxf(acc, 0.f);
    }
    __syncthreads();
    float z = 0.f;
    #pragma unroll
    for (int c = 0; c < 64; ++c) z = fmaf(wse2[tid*64 + c], y1[c], z);
    float se = 1.f / (1.f + expf(-z));
    const int bc = bb*HID + tid;
    float al = g_stats[SIS3 + bc] * se;
    if (tid >= 32 && tid < 64) al = 0.f;   // zero-TIM channels: exact zero contribution
    g_stats[SAL + bc] = al;
    g_stats[SBE + bc] = -g_stats[SM3 + bc] * al;
}

// ============ proj 1x1 via MFMA (uint2 B-stage, alpha==0 skip) ================
// epilogue additionally reduces per-channel partial sums of the f32 outputs so
// k_final can skip its whole stats pass over proj.
__global__ __launch_bounds__(256) void k_proj(const ushort_t* __restrict__ h3,
                                              float* __restrict__ proj) {
    __shared__ ushort_t Bs[64*136];      // B[klocal][n], stride 136, rotated cols
    __shared__ float rs[64][4], rss[64][4];
    const int tid = threadIdx.x;
    const int bb  = blockIdx.y;
    const int pos0 = blockIdx.x * 128;
    const int lane = tid & 63, wv = tid >> 6;
    const int q = lane >> 4, ln = lane & 15;

    f32x4 acc[4][2];
    #pragma unroll
    for (int i = 0; i < 4; ++i) {
        acc[i][0] = (f32x4){0.f,0.f,0.f,0.f};
        acc[i][1] = (f32x4){0.f,0.f,0.f,0.f};
    }

    for (int kc = 0; kc < 4; ++kc) {
        #pragma unroll
        for (int i = 0; i < 8; ++i) {
            int lin = i*1024 + tid*4;
            int kl = lin >> 7, n0 = lin & 127;
            int ch = bb*HID + kc*64 + kl;
            float al = g_stats[SAL + ch], be = g_stats[SBE + ch];
            ushort_t* d = &Bs[kl*136 + ((n0 + 16*((kl>>3)&7)) & 127)];
            if (al == 0.f) {                 // zero-forced TIM channels
                d[0] = 0; d[1] = 0; d[2] = 0; d[3] = 0;
            } else {
                uint2 u = *(const uint2*)&h3[(size_t)ch * THW + pos0 + n0];
                float f0 = __uint_as_float(u.x << 16);
                float f1 = __uint_as_float(u.x & 0xffff0000u);
                float f2 = __uint_as_float(u.y << 16);
                float f3 = __uint_as_float(u.y & 0xffff0000u);
                d[0] = f2bf(fmaxf(fmaf(f0, al, be), 0.f));
                d[1] = f2bf(fmaxf(fmaf(f1, al, be), 0.f));
                d[2] = f2bf(fmaxf(fmaf(f2, al, be), 0.f));
                d[3] = f2bf(fmaxf(fmaf(f3, al, be), 0.f));
            }
        }
        __syncthreads();

        #pragma unroll
        for (int ks = 0; ks < 2; ++ks) {
            int kg = kc*2 + ks;
            bf16x8 af[4];
            #pragma unroll
            for (int ot = 0; ot < 4; ++ot)
                af[ot] = *(const bf16x8*)&g_wpack[16384 + ((kg*4+ot)<<9) + lane*8];
            bf16x8 bfr[2];
            #pragma unroll
            for (int nt = 0; nt < 2; ++nt) {
                union { short s[8]; bf16x8 v; } bu;
                #pragma unroll
                for (int j = 0; j < 8; ++j) {
                    int kl = ks*32 + q*8 + j;
                    int nn = (wv*32 + nt*16 + ln + 16*((kl>>3)&7)) & 127;
                    bu.s[j] = (short)Bs[kl*136 + nn];
                }
                bfr[nt] = bu.v;
            }
            #pragma unroll
            for (int ot = 0; ot < 4; ++ot)
                #pragma unroll
                for (int nt = 0; nt < 2; ++nt)
                    acc[ot][nt] = __builtin_amdgcn_mfma_f32_16x16x32_bf16(
                        af[ot], bfr[nt], acc[ot][nt], 0, 0, 0);
        }
        __syncthreads();
    }

    #pragma unroll
    for (int ot = 0; ot < 4; ++ot)
        #pragma unroll
        for (int nt = 0; nt < 2; ++nt)
            #pragma unroll
            for (int r = 0; r < 4; ++r) {
                int o = ot*16 + q*4 + r;
                int n = wv*32 + nt*16 + ln;
                proj[((size_t)bb*COUT + o)*THW + pos0 + n] = acc[ot][nt][r];
            }

    // per-channel partial sums over this 128-position block (f32 == stored proj)
    #pragma unroll
    for (int ot = 0; ot < 4; ++ot)
        #pragma unroll
        for (int r = 0; r < 4; ++r) {
            float s  = acc[ot][0][r] + acc[ot][1][r];
            float ss = fmaf(acc[ot][0][r], acc[ot][0][r],
                            acc[ot][1][r] * acc[ot][1][r]);
            #pragma unroll
            for (int m = 1; m < 16; m <<= 1) {
                s  += __shfl_xor(s,  m);
                ss += __shfl_xor(ss, m);
            }
            if (ln == 0) {
                int o = ot*16 + q*4 + r;
                rs[o][wv]  = s;
                rss[o][wv] = ss;
            }
        }
    __syncthreads();
    if (tid < 64) {
        float s  = rs[tid][0]  + rs[tid][1]  + rs[tid][2]  + rs[tid][3];
        float ss = rss[tid][0] + rss[tid][1] + rss[tid][2] + rss[tid][3];
        size_t base = ((size_t)bb*64 + tid)*512 + blockIdx.x;
        g_pps [base] = s;
        g_ppss[base] = ss;
    }
}

// ------------ final fused: norm + shortcut + maxpool (stats from partials) ----
__global__ __launch_bounds__(1024) void k_final(const float* __restrict__ proj,
                                                const float* __restrict__ x,
                                                float* __restrict__ out, int b0) {
    const int bo  = blockIdx.x;
    const int tid = threadIdx.x;
    const float* p = proj + (size_t)bo * THW;

    float s = 0.f, ss = 0.f;
    if (tid < 512) {
        s  = g_pps [(size_t)bo*512 + tid];
        ss = g_ppss[(size_t)bo*512 + tid];
    }
    #pragma unroll
    for (int off = 32; off > 0; off >>= 1) {
        s  += __shfl_down(s,  off, 64);
        ss += __shfl_down(ss, off, 64);
    }
    __shared__ float ls[16], lss[16];
    __shared__ float sa, sb;
    int wid = tid >> 6, lane = tid & 63;
    if (lane == 0) { ls[wid] = s; lss[wid] = ss; }
    __syncthreads();
    if (tid == 0) {
        float st = 0.f, sst = 0.f;
        #pragma unroll
        for (int i = 0; i < 16; ++i) { st += ls[i]; sst += lss[i]; }
        float m = st * (1.f/THW);
        float v = sst * (1.f/THW) - m*m;
        float is = 1.f / sqrtf(v + EPS);
        sa = is; sb = -m * is;
    }
    __syncthreads();
    const float a = sa, bb = sb;

    const size_t gbase = (size_t)(b0*COUT + bo) * THW;
    float* op = out + (size_t)(b0*COUT + bo) * (T_*1024);
    #pragma unroll
    for (int i = 0; i < 16; ++i) {
        int idx = i*1024 + tid;
        int xx = idx & 31, yy = (idx >> 5) & 31, t = idx >> 10;
        float m = -3.4e38f;
        #pragma unroll
        for (int r = 0; r < 2; ++r) {
            size_t off = (size_t)t*HW_ + (size_t)(2*yy + r)*W_ + 2*xx;
            float2 p2 = *(const float2*)(p + off);
            float2 x2 = *(const float2*)(x + gbase + off);
            float v0 = fmaf(p2.x, a, bb) + x2.x;
            float v1 = fmaf(p2.y, a, bb) + x2.y;
            m = fmaxf(m, fmaxf(v0, v1));
        }
        op[idx] = m;
    }
}

extern "C" void kernel_launch(void* const* d_in, const int* in_sizes, int n_in,
                              void* d_out, int out_size, void* d_ws, size_t ws_size,
                              hipStream_t stream) {
    const float* x     = (const float*)d_in[0];
    const float* w1    = (const float*)d_in[1];
    const float* wdws  = (const float*)d_in[2];
    const float* wdwt  = (const float*)d_in[3];
    const float* wse1  = (const float*)d_in[4];
    const float* wse2  = (const float*)d_in[5];
    const float* wproj = (const float*)d_in[6];
    float* out = (float*)d_out;

    const size_t perb = 2ull * HID * THW * sizeof(ushort_t);   // 64 MB
    int nb = (ws_size >= 4*perb) ? 4 : (ws_size >= 2*perb) ? 2 : 1;

    k_prep<<<64, 256, 0, stream>>>(w1, wproj);

    for (int b0 = 0; b0 < B_; b0 += nb) {
        char* ws = (char*)d_ws;
        ushort_t* h1   = (ushort_t*)ws;
        ushort_t* h3   = h1;                                   // in-place per channel
        float*    proj = (float*)(ws + (size_t)nb * HID*THW*2);

        k_expand<<<dim3(THW/64, nb), 256, 0, stream>>>(x, h1, b0);
        k_mid   <<<nb*HID, 1024, 0, stream>>>(h1, wdws, wdwt, h3);
        k_semlp <<<nb, 256, 0, stream>>>(wse1, wse2);
        k_proj  <<<dim3(THW/128, nb), 256, 0, stream>>>(h3, proj);
        k_final <<<nb*COUT, 1024, 0, stream>>>(proj, x, out, b0);
    }
}

// Round 13
// 354.904 us; speedup vs baseline: 1.0604x; 1.0604x over previous
//
#include <hip/hip_runtime.h>
#include <hip/hip_bf16.h>

#define B_   4
#define CIN  64
#define HID  256
#define COUT 64
#define T_   16
#define H_   64
#define W_   64
#define HW_  (H_*W_)       // 4096
#define THW  (T_*HW_)      // 65536
#define EPS  1e-5f

typedef unsigned short ushort_t;
typedef unsigned int   uint_t;
typedef short bf16x8 __attribute__((ext_vector_type(8)));
typedef float f32x4  __attribute__((ext_vector_type(4)));

// ---- stats in static device memory -------------------------------------------
#define SA1   0        // stats1 alpha (inv_sd) per (bb,ch)   <- k_red
#define SB1   1024     // stats1 beta  (-m*inv_sd)            <- k_red
#define SM3   4096
#define SIS3  5120
#define SSES  6144
#define SAL   7168
#define SBE   8192
__device__ float g_stats[10240];
// per-(bb, pos-block, channel) partial sums from k_expand epilogue (stats1).
// layout [bb][posblk][ch]: k_expand's write (tid=ch) is COALESCED (the hot
// side, R5/R12-validated); k_red does the transpose-reduction (L2-hot).
__device__ float g_eps [4*1024*256];
__device__ float g_epss[4*1024*256];
// packed bf16 weights in MFMA fragment order: [0:16384) expand, [16384:32768) proj
__device__ ushort_t g_wpack[32768];

__device__ __forceinline__ float bf2f(ushort_t u) {
    return __uint_as_float(((uint_t)u) << 16);
}
__device__ __forceinline__ ushort_t f2bf(float f) {
    uint_t u = __float_as_uint(f);
    uint_t r = u + 0x7fffu + ((u >> 16) & 1u);   // round-to-nearest-even
    return (ushort_t)(r >> 16);
}
__device__ __forceinline__ void unpacknorm2(uint2 k, float a, float bb, float* v) {
    uint_t uu[2] = {k.x, k.y};
    #pragma unroll
    for (int j = 0; j < 2; ++j) {
        v[2*j]   = fmaxf(fmaf(__uint_as_float(uu[j] << 16),         a, bb), 0.f);
        v[2*j+1] = fmaxf(fmaf(__uint_as_float(uu[j] & 0xffff0000u), a, bb), 0.f);
    }
}

// ---- pack w1 + wproj into bf16 fragment order --------------------------------
__global__ __launch_bounds__(256) void k_prep(const float* __restrict__ w1,
                                              const float* __restrict__ wproj) {
    int idx = blockIdx.x*256 + threadIdx.x;        // 0..16383
    {
        int j = idx & 7, lane = (idx>>3) & 63, ot = (idx>>9) & 3;
        int ks = (idx>>11) & 1, wv = idx >> 12;
        int ln = lane & 15, q = lane >> 4;
        int o = wv*64 + ot*16 + ln, k = ks*32 + q*8 + j;
        g_wpack[idx] = f2bf(w1[o*CIN + k]);
    }
    {
        int j = idx & 7, lane = (idx>>3) & 63, ot = (idx>>9) & 3, kg = idx >> 11;
        int ln = lane & 15, q = lane >> 4;
        int o = ot*16 + ln, k = kg*32 + q*8 + j;
        g_wpack[16384 + idx] = f2bf(wproj[o*HID + k]);
    }
}

// ============ expand 1x1 via MFMA + fused per-channel stats1 partials =========
__global__ __launch_bounds__(256) void k_expand(const float* __restrict__ x,
                                                ushort_t* __restrict__ h1, int b0) {
    union SMem {
        ushort_t Bs[64*72];          // B[k][n], stride 72, rotated cols (18.4 KB)
        float    red[2][256][16];    // per-channel per-16lane partials (32 KB)
    };
    __shared__ SMem sm;
    const int tid = threadIdx.x;
    const int bb  = blockIdx.y, gb = b0 + bb;
    const int pos0 = blockIdx.x * 64;
    const int lane = tid & 63, wv = tid >> 6;
    const int q = lane >> 4, ln = lane & 15;

    bf16x8 af[2][4];
    #pragma unroll
    for (int ks = 0; ks < 2; ++ks)
        #pragma unroll
        for (int ot = 0; ot < 4; ++ot)
            af[ks][ot] = *(const bf16x8*)&g_wpack[(((wv*2+ks)*4+ot)<<9) + lane*8];

    #pragma unroll
    for (int i = 0; i < 4; ++i) {
        int lin = i*1024 + tid*4;
        int k = lin >> 6, n0 = lin & 63;
        float4 v = *(const float4*)&x[(size_t)(gb*CIN + k) * THW + pos0 + n0];
        ushort_t* d = &sm.Bs[k*72 + ((n0 + 16*((k>>3)&3)) & 63)];
        d[0] = f2bf(v.x); d[1] = f2bf(v.y); d[2] = f2bf(v.z); d[3] = f2bf(v.w);
    }
    __syncthreads();

    f32x4 acc[4][4];
    #pragma unroll
    for (int i = 0; i < 4; ++i)
        #pragma unroll
        for (int j = 0; j < 4; ++j)
            acc[i][j] = (f32x4){0.f,0.f,0.f,0.f};

    #pragma unroll
    for (int ks = 0; ks < 2; ++ks) {
        bf16x8 bfr[4];
        #pragma unroll
        for (int nt = 0; nt < 4; ++nt) {
            union { short s[8]; bf16x8 v; } bu;
            #pragma unroll
            for (int j = 0; j < 8; ++j) {
                int k = ks*32 + q*8 + j;
                int nn = (nt*16 + ln + 16*((k>>3)&3)) & 63;
                bu.s[j] = (short)sm.Bs[k*72 + nn];
            }
            bfr[nt] = bu.v;
        }
        #pragma unroll
        for (int ot = 0; ot < 4; ++ot)
            #pragma unroll
            for (int nt = 0; nt < 4; ++nt)
                acc[ot][nt] = __builtin_amdgcn_mfma_f32_16x16x32_bf16(
                    af[ks][ot], bfr[nt], acc[ot][nt], 0, 0, 0);
    }

    // epilogue: store + accumulate per-lane per-channel partial sums
    float sp_[16], ssp_[16];
    #pragma unroll
    for (int i = 0; i < 16; ++i) { sp_[i] = 0.f; ssp_[i] = 0.f; }

    #pragma unroll
    for (int ot = 0; ot < 4; ++ot)
        #pragma unroll
        for (int nt = 0; nt < 4; ++nt)
            #pragma unroll
            for (int r = 0; r < 4; ++r) {
                float vv = acc[ot][nt][r];
                int o = wv*64 + ot*16 + q*4 + r;
                int n = nt*16 + ln;
                h1[((size_t)bb*HID + o)*THW + pos0 + n] = f2bf(vv);
                sp_[ot*4+r] += vv;
                ssp_[ot*4+r] = fmaf(vv, vv, ssp_[ot*4+r]);
            }

    __syncthreads();           // all waves done reading Bs before union reuse
    #pragma unroll
    for (int i = 0; i < 16; ++i) {
        int o = wv*64 + (i>>2)*16 + q*4 + (i&3);
        sm.red[0][o][ln] = sp_[i];
        sm.red[1][o][ln] = ssp_[i];
    }
    __syncthreads();
    {
        float s = 0.f, ss = 0.f;
        #pragma unroll
        for (int l = 0; l < 16; ++l) {
            s  += sm.red[0][tid][l];
            ss += sm.red[1][tid][l];
        }
        size_t base = ((size_t)bb*1024 + blockIdx.x)*256 + tid;   // coalesced
        g_eps [base] = s;
        g_epss[base] = ss;
    }
}

// ---- stats1 transpose-reduction: g_eps [bb][posblk][ch] -> (a1,b1) per ch ----
// 16 ch-groups x nb blocks, 256 thr (16 posblk x 16 ch tile); 8 MB L2-hot read.
__global__ __launch_bounds__(256) void k_red() {
    const int tid = threadIdx.x;
    const int cg  = blockIdx.x;          // 0..15
    const int bb  = blockIdx.y;
    const int ch  = cg*16 + (tid & 15);
    const int pb0 = tid >> 4;            // 0..15
    const float* ps  = &g_eps [((size_t)bb*1024)*256];
    const float* pss = &g_epss[((size_t)bb*1024)*256];
    float s = 0.f, ss = 0.f;
    #pragma unroll 8
    for (int it = 0; it < 64; ++it) {
        int pb = it*16 + pb0;
        s  += ps [(size_t)pb*256 + ch];
        ss += pss[(size_t)pb*256 + ch];
    }
    __shared__ float rs[256], rss[256];
    rs[tid] = s; rss[tid] = ss;
    __syncthreads();
    if (tid < 16) {
        float st = 0.f, sst = 0.f;
        #pragma unroll
        for (int k = 0; k < 16; ++k) { st += rs[tid + 16*k]; sst += rss[tid + 16*k]; }
        float m = st * (1.f/THW);
        float v = sst * (1.f/THW) - m*m;
        float is = 1.f / sqrtf(v + EPS);
        int bc = bb*HID + cg*16 + tid;
        g_stats[SA1 + bc] = is;
        g_stats[SB1 + bc] = -m * is;
    }
}

// ===== fused stage2+stage3: spatial dw3x3 -> IN -> relu -> temporal dw3 =======
// one block (1024 thr) per (bb, channel); dws output in keep[16] uint2 registers.
// Halo-padded LDS plane removes all boundary branches; T14 reg-staging (load
// plane t+2 at iter t, LDS-write at t+1) hides the h1 read latency under a full
// conv phase. Stats1 comes precomputed from k_red (2 scalar loads). NO forced
// min-occupancy (R8: (1024,8) forces spill; unforced = 48 VGPR, no spill, R11).
__global__ __launch_bounds__(1024) void k_mid(const ushort_t* __restrict__ h1,
                                              const float* __restrict__ wdws,
                                              const float* __restrict__ wdwt,
                                              ushort_t* __restrict__ h3) {
    const int tid = threadIdx.x;                  // 0..1023
    const int bc  = blockIdx.x;
    const int o   = bc & (HID-1);
    const int bb  = bc >> 8;
    const int wid = tid >> 6, lane = tid & 63;

    if (o >= 32 && o < 64) {                      // zero-forced TIM channels
        if (tid == 0) {
            g_stats[SM3  + bc] = 0.f;
            g_stats[SIS3 + bc] = 1.f / sqrtf(EPS);
            g_stats[SSES + bc] = 0.f;
        }
        return;
    }

    __shared__ float pl[2][66*67];                // halo-padded norm'd planes
    __shared__ float ls[16], lss[16];
    __shared__ float sa, sb;

    const float a1 = g_stats[SA1 + bc];
    const float b1 = g_stats[SB1 + bc];

    // halo zero (both buffers)
    if (tid < 66) {
        #pragma unroll
        for (int b = 0; b < 2; ++b) {
            pl[b][tid]         = 0.f;             // row 0
            pl[b][65*67 + tid] = 0.f;             // row 65
            pl[b][tid*67]      = 0.f;             // col 0
            pl[b][tid*67 + 65] = 0.f;             // col 65
        }
    }

    const int fut = (o < 32) ? 1 : 0;             // TIM future-shifted channel
    const int y   = tid >> 4;                     // 0..63
    const int x0  = (tid & 15) * 4;               // 0..60
    const ushort_t* chp = h1 + (size_t)bc * THW;
    const int lastp = fut ? (T_-2) : (T_-1);      // last plane with real input

    float wf[9];
    #pragma unroll
    for (int k = 0; k < 9; ++k) wf[k] = wdws[o*9 + k];

    // prologue: plane 0 staged (latency exposed once), plane 1 load in flight
    uint2 sreg[2];
    sreg[0] = *(const uint2*)(chp + (size_t)fut*HW_ + tid*4);
    {
        float vv[4];
        unpacknorm2(sreg[0], a1, b1, vv);
        float* dst = &pl[0][(y+1)*67 + x0 + 1];
        #pragma unroll
        for (int i = 0; i < 4; ++i) dst[i] = vv[i];
    }
    sreg[1] = *(const uint2*)(chp + (size_t)(1+fut)*HW_ + tid*4);
    __syncthreads();

    // ---- phase A: spatial 3x3 conv, outputs kept in registers ----------------
    uint2 keep[16];
    float s2 = 0.f, ss2 = 0.f;

    #pragma unroll
    for (int t = 0; t < T_; ++t) {
        // issue raw load for plane t+2 (consumed next iteration)
        if (t + 2 <= lastp)
            sreg[t & 1] = *(const uint2*)(chp + (size_t)(t+2+fut)*HW_ + tid*4);
        // normalize + LDS-write plane t+1 (loaded one iteration ago)
        if (t + 1 <= lastp) {
            float vv[4];
            unpacknorm2(sreg[(t+1) & 1], a1, b1, vv);
            float* dst = &pl[(t+1) & 1][(y+1)*67 + x0 + 1];
            #pragma unroll
            for (int i = 0; i < 4; ++i) dst[i] = vv[i];
        }
        if (fut && t == T_-1) {
            keep[t] = (uint2){0u, 0u};            // TIM zero plane: dws out = 0
        } else {
            const float* plane = pl[t & 1];
            float v[3][6];
            #pragma unroll
            for (int dy = 0; dy < 3; ++dy) {
                const float* rp = &plane[(y + dy)*67 + x0];
                #pragma unroll
                for (int j = 0; j < 6; ++j) v[dy][j] = rp[j];
            }
            uint_t outp[2];
            #pragma unroll
            for (int i2 = 0; i2 < 2; ++i2) {
                float o0 = 0.f, o1 = 0.f;
                #pragma unroll
                for (int dy = 0; dy < 3; ++dy)
                    #pragma unroll
                    for (int dx = 0; dx < 3; ++dx) {
                        float w = wf[dy*3+dx];
                        o0 = fmaf(w, v[dy][2*i2 + dx],     o0);
                        o1 = fmaf(w, v[dy][2*i2 + 1 + dx], o1);
                    }
                ushort_t u0 = f2bf(o0), u1 = f2bf(o1);
                float r0 = bf2f(u0), r1 = bf2f(u1);
                s2 += r0 + r1; ss2 = fmaf(r0, r0, fmaf(r1, r1, ss2));
                outp[i2] = (uint_t)u0 | ((uint_t)u1 << 16);
            }
            keep[t].x = outp[0]; keep[t].y = outp[1];
        }
        __syncthreads();
    }

    // ---- phase B: stats2 block-reduce (never touches HBM) --------------------
    {
        float s = s2, ss = ss2;
        #pragma unroll
        for (int m = 32; m > 0; m >>= 1) {
            s  += __shfl_xor(s,  m);
            ss += __shfl_xor(ss, m);
        }
        if (lane == 0) { ls[wid] = s; lss[wid] = ss; }
        __syncthreads();
        if (tid == 0) {
            float st = 0.f, sst = 0.f;
            #pragma unroll
            for (int i = 0; i < 16; ++i) { st += ls[i]; sst += lss[i]; }
            float m = st * (1.f/THW);
            float v = sst * (1.f/THW) - m*m;
            float is = 1.f / sqrtf(v + EPS);
            sa = is; sb = -m * is;
        }
        __syncthreads();
    }
    const float a2 = sa, b2 = sb;
    // note: for fut channels keep[15]==0 -> unpacknorm2 gives relu(b2) == znorm

    // ---- phase C: temporal dw3 from registers, write h3, stats3 --------------
    const float w0 = wdwt[o*3+0], w1 = wdwt[o*3+1], w2 = wdwt[o*3+2];
    ushort_t* op = h3 + (size_t)bc * THW + tid*4;

    float p[4], c[4], n[4];
    #pragma unroll
    for (int i = 0; i < 4; ++i) p[i] = 0.f;
    unpacknorm2(keep[0], a2, b2, c);
    unpacknorm2(keep[1], a2, b2, n);

    float s3 = 0.f, ss3 = 0.f;
    #pragma unroll
    for (int t = 0; t < T_; ++t) {
        uint_t outp[2];
        #pragma unroll
        for (int i2 = 0; i2 < 2; ++i2) {
            float o0 = fmaf(w0, p[2*i2],   fmaf(w1, c[2*i2],   w2 * n[2*i2]));
            float o1 = fmaf(w0, p[2*i2+1], fmaf(w1, c[2*i2+1], w2 * n[2*i2+1]));
            ushort_t u0 = f2bf(o0), u1 = f2bf(o1);
            float r0 = bf2f(u0), r1 = bf2f(u1);
            s3 += r0 + r1; ss3 = fmaf(r0, r0, fmaf(r1, r1, ss3));
            outp[i2] = (uint_t)u0 | ((uint_t)u1 << 16);
        }
        uint2 r; r.x = outp[0]; r.y = outp[1];
        *(uint2*)(op + (size_t)t*HW_) = r;

        #pragma unroll
        for (int i = 0; i < 4; ++i) { p[i] = c[i]; c[i] = n[i]; }
        if (t + 2 < T_) unpacknorm2(keep[t+2], a2, b2, n);
        else {
            #pragma unroll
            for (int i = 0; i < 4; ++i) n[i] = 0.f;   // true conv zero-padding
        }
        keep[t] = r;                                   // reuse for SE-mean pass
    }

    {
        float s = s3, ss = ss3;
        #pragma unroll
        for (int m = 32; m > 0; m >>= 1) {
            s  += __shfl_xor(s,  m);
            ss += __shfl_xor(ss, m);
        }
        if (lane == 0) { ls[wid] = s; lss[wid] = ss; }
        __syncthreads();
        if (tid == 0) {
            float st = 0.f, sst = 0.f;
            #pragma unroll
            for (int i = 0; i < 16; ++i) { st += ls[i]; sst += lss[i]; }
            float m = st * (1.f/THW);
            float v = sst * (1.f/THW) - m*m;
            float is = 1.f / sqrtf(v + EPS);
            g_stats[SM3  + bc] = m;
            g_stats[SIS3 + bc] = is;
            sa = is; sb = -m * is;
        }
        __syncthreads();
    }

    // ---- phase D: SE mean of relu(norm3(h3)) from kept registers -------------
    const float a3 = sa, b3 = sb;
    float sse = 0.f;
    #pragma unroll
    for (int t = 0; t < T_; ++t) {
        uint_t uu[2] = {keep[t].x, keep[t].y};
        #pragma unroll
        for (int j = 0; j < 2; ++j) {
            sse += fmaxf(fmaf(__uint_as_float(uu[j] << 16),         a3, b3), 0.f);
            sse += fmaxf(fmaf(__uint_as_float(uu[j] & 0xffff0000u), a3, b3), 0.f);
        }
    }
    #pragma unroll
    for (int m = 32; m > 0; m >>= 1) sse += __shfl_xor(sse, m);
    if (lane == 0) ls[wid] = sse;
    __syncthreads();
    if (tid == 0) {
        float st = 0.f;
        #pragma unroll
        for (int i = 0; i < 16; ++i) st += ls[i];
        g_stats[SSES + bc] = st * (1.f/THW);
    }
}

// ------------ SE MLP -> fold sigmoid scale into proj's alpha/beta -------------
__global__ __launch_bounds__(256) void k_semlp(const float* __restrict__ wse1,
                                               const float* __restrict__ wse2) {
    __shared__ float mv[HID];
    __shared__ float y1[64];
    const int bb = blockIdx.x, tid = threadIdx.x;
    mv[tid] = g_stats[SSES + bb*HID + tid];
    __syncthreads();
    if (tid < 64) {
        float acc = 0.f;
        #pragma unroll 8
        for (int c = 0; c < HID; ++c) acc = fmaf(wse1[tid*HID + c], mv[c], acc);
        y1[tid] = fmaxf(acc, 0.f);
    }
    __syncthreads();
    float z = 0.f;
    #pragma unroll
    for (int c = 0; c < 64; ++c) z = fmaf(wse2[tid*64 + c], y1[c], z);
    float se = 1.f / (1.f + expf(-z));
    const int bc = bb*HID + tid;
    float al = g_stats[SIS3 + bc] * se;
    if (tid >= 32 && tid < 64) al = 0.f;   // zero-TIM channels: exact zero contribution
    g_stats[SAL + bc] = al;
    g_stats[SBE + bc] = -g_stats[SM3 + bc] * al;
}

// ============ proj 1x1 via MFMA (uint2 B-stage, alpha==0 skip) ================
// R5 version: no epilogue (R12 measured the partials machinery at net +15 us).
__global__ __launch_bounds__(256) void k_proj(const ushort_t* __restrict__ h3,
                                              float* __restrict__ proj) {
    __shared__ ushort_t Bs[64*136];      // B[klocal][n], stride 136, rotated cols
    const int tid = threadIdx.x;
    const int bb  = blockIdx.y;
    const int pos0 = blockIdx.x * 128;
    const int lane = tid & 63, wv = tid >> 6;
    const int q = lane >> 4, ln = lane & 15;

    f32x4 acc[4][2];
    #pragma unroll
    for (int i = 0; i < 4; ++i) {
        acc[i][0] = (f32x4){0.f,0.f,0.f,0.f};
        acc[i][1] = (f32x4){0.f,0.f,0.f,0.f};
    }

    for (int kc = 0; kc < 4; ++kc) {
        #pragma unroll
        for (int i = 0; i < 8; ++i) {
            int lin = i*1024 + tid*4;
            int kl = lin >> 7, n0 = lin & 127;
            int ch = bb*HID + kc*64 + kl;
            float al = g_stats[SAL + ch], be = g_stats[SBE + ch];
            ushort_t* d = &Bs[kl*136 + ((n0 + 16*((kl>>3)&7)) & 127)];
            if (al == 0.f) {                 // zero-forced TIM channels
                d[0] = 0; d[1] = 0; d[2] = 0; d[3] = 0;
            } else {
                uint2 u = *(const uint2*)&h3[(size_t)ch * THW + pos0 + n0];
                float f0 = __uint_as_float(u.x << 16);
                float f1 = __uint_as_float(u.x & 0xffff0000u);
                float f2 = __uint_as_float(u.y << 16);
                float f3 = __uint_as_float(u.y & 0xffff0000u);
                d[0] = f2bf(fmaxf(fmaf(f0, al, be), 0.f));
                d[1] = f2bf(fmaxf(fmaf(f1, al, be), 0.f));
                d[2] = f2bf(fmaxf(fmaf(f2, al, be), 0.f));
                d[3] = f2bf(fmaxf(fmaf(f3, al, be), 0.f));
            }
        }
        __syncthreads();

        #pragma unroll
        for (int ks = 0; ks < 2; ++ks) {
            int kg = kc*2 + ks;
            bf16x8 af[4];
            #pragma unroll
            for (int ot = 0; ot < 4; ++ot)
                af[ot] = *(const bf16x8*)&g_wpack[16384 + ((kg*4+ot)<<9) + lane*8];
            bf16x8 bfr[2];
            #pragma unroll
            for (int nt = 0; nt < 2; ++nt) {
                union { short s[8]; bf16x8 v; } bu;
                #pragma unroll
                for (int j = 0; j < 8; ++j) {
                    int kl = ks*32 + q*8 + j;
                    int nn = (wv*32 + nt*16 + ln + 16*((kl>>3)&7)) & 127;
                    bu.s[j] = (short)Bs[kl*136 + nn];
                }
                bfr[nt] = bu.v;
            }
            #pragma unroll
            for (int ot = 0; ot < 4; ++ot)
                #pragma unroll
                for (int nt = 0; nt < 2; ++nt)
                    acc[ot][nt] = __builtin_amdgcn_mfma_f32_16x16x32_bf16(
                        af[ot], bfr[nt], acc[ot][nt], 0, 0, 0);
        }
        __syncthreads();
    }

    #pragma unroll
    for (int ot = 0; ot < 4; ++ot)
        #pragma unroll
        for (int nt = 0; nt < 2; ++nt)
            #pragma unroll
            for (int r = 0; r < 4; ++r) {
                int o = ot*16 + q*4 + r;
                int n = wv*32 + nt*16 + ln;
                proj[((size_t)bb*COUT + o)*THW + pos0 + n] = acc[ot][nt][r];
            }
}

// ------------ final fused: proj stats + norm + shortcut + maxpool (R5) --------
__global__ __launch_bounds__(1024) void k_final(const float* __restrict__ proj,
                                                const float* __restrict__ x,
                                                float* __restrict__ out, int b0) {
    const int bo  = blockIdx.x;
    const int tid = threadIdx.x;
    const float* p = proj + (size_t)bo * THW;

    float s = 0.f, ss = 0.f;
    #pragma unroll
    for (int i = 0; i < THW/(1024*4); ++i) {
        float4 u = *(const float4*)(p + i*4096 + tid*4);
        s += u.x; ss = fmaf(u.x, u.x, ss);
        s += u.y; ss = fmaf(u.y, u.y, ss);
        s += u.z; ss = fmaf(u.z, u.z, ss);
        s += u.w; ss = fmaf(u.w, u.w, ss);
    }
    #pragma unroll
    for (int off = 32; off > 0; off >>= 1) {
        s  += __shfl_down(s,  off, 64);
        ss += __shfl_down(ss, off, 64);
    }
    __shared__ float ls[16], lss[16];
    __shared__ float sa, sb;
    int wid = tid >> 6, lane = tid & 63;
    if (lane == 0) { ls[wid] = s; lss[wid] = ss; }
    __syncthreads();
    if (tid == 0) {
        float st = 0.f, sst = 0.f;
        #pragma unroll
        for (int i = 0; i < 16; ++i) { st += ls[i]; sst += lss[i]; }
        float m = st * (1.f/THW);
        float v = sst * (1.f/THW) - m*m;
        float is = 1.f / sqrtf(v + EPS);
        sa = is; sb = -m * is;
    }
    __syncthreads();
    const float a = sa, bb = sb;

    const size_t gbase = (size_t)(b0*COUT + bo) * THW;
    float* op = out + (size_t)(b0*COUT + bo) * (T_*1024);
    #pragma unroll
    for (int i = 0; i < 16; ++i) {
        int idx = i*1024 + tid;
        int xx = idx & 31, yy = (idx >> 5) & 31, t = idx >> 10;
        float m = -3.4e38f;
        #pragma unroll
        for (int r = 0; r < 2; ++r) {
            size_t off = (size_t)t*HW_ + (size_t)(2*yy + r)*W_ + 2*xx;
            float2 p2 = *(const float2*)(p + off);
            float2 x2 = *(const float2*)(x + gbase + off);
            float v0 = fmaf(p2.x, a, bb) + x2.x;
            float v1 = fmaf(p2.y, a, bb) + x2.y;
            m = fmaxf(m, fmaxf(v0, v1));
        }
        op[idx] = m;
    }
}

extern "C" void kernel_launch(void* const* d_in, const int* in_sizes, int n_in,
                              void* d_out, int out_size, void* d_ws, size_t ws_size,
                              hipStream_t stream) {
    const float* x     = (const float*)d_in[0];
    const float* w1    = (const float*)d_in[1];
    const float* wdws  = (const float*)d_in[2];
    const float* wdwt  = (const float*)d_in[3];
    const float* wse1  = (const float*)d_in[4];
    const float* wse2  = (const float*)d_in[5];
    const float* wproj = (const float*)d_in[6];
    float* out = (float*)d_out;

    const size_t perb = 2ull * HID * THW * sizeof(ushort_t);   // 64 MB
    int nb = (ws_size >= 4*perb) ? 4 : (ws_size >= 2*perb) ? 2 : 1;

    k_prep<<<64, 256, 0, stream>>>(w1, wproj);

    for (int b0 = 0; b0 < B_; b0 += nb) {
        char* ws = (char*)d_ws;
        ushort_t* h1   = (ushort_t*)ws;
        ushort_t* h3   = h1;                                   // in-place per channel
        float*    proj = (float*)(ws + (size_t)nb * HID*THW*2);

        k_expand<<<dim3(THW/64, nb), 256, 0, stream>>>(x, h1, b0);
        k_red   <<<dim3(16, nb), 256, 0, stream>>>();
        k_mid   <<<nb*HID, 1024, 0, stream>>>(h1, wdws, wdwt, h3);
        k_semlp <<<nb, 256, 0, stream>>>(wse1, wse2);
        k_proj  <<<dim3(THW/128, nb), 256, 0, stream>>>(h3, proj);
        k_final <<<nb*COUT, 1024, 0, stream>>>(proj, x, out, b0);
    }
}

// Round 18
// 351.204 us; speedup vs baseline: 1.0716x; 1.0105x over previous
//
#include <hip/hip_runtime.h>
#include <hip/hip_bf16.h>

#define B_   4
#define CIN  64
#define HID  256
#define COUT 64
#define T_   16
#define H_   64
#define W_   64
#define HW_  (H_*W_)       // 4096
#define THW  (T_*HW_)      // 65536
#define EPS  1e-5f

typedef unsigned short ushort_t;
typedef unsigned int   uint_t;
typedef short bf16x8 __attribute__((ext_vector_type(8)));
typedef float f32x4  __attribute__((ext_vector_type(4)));

// ---- stats in static device memory -------------------------------------------
#define SA1   0        // stats1 alpha (inv_sd) per (bb,ch)   <- k_red
#define SB1   1024     // stats1 beta  (-m*inv_sd)            <- k_red
#define SM3   4096
#define SIS3  5120
#define SSES  6144
#define SAL   7168
#define SBE   8192
__device__ float g_stats[10240];
// per-(bb, pos-block, channel) partial sums from k_expand epilogue (stats1).
// layout [bb][posblk][ch]: k_expand's write (tid=ch) is COALESCED (the hot
// side, R5/R12-validated); k_red does the transpose-reduction (L2-hot).
__device__ float g_eps [4*1024*256];
__device__ float g_epss[4*1024*256];
// packed bf16 weights in MFMA fragment order: [0:16384) expand, [16384:32768) proj
__device__ ushort_t g_wpack[32768];

__device__ __forceinline__ float bf2f(ushort_t u) {
    return __uint_as_float(((uint_t)u) << 16);
}
__device__ __forceinline__ ushort_t f2bf(float f) {
    uint_t u = __float_as_uint(f);
    uint_t r = u + 0x7fffu + ((u >> 16) & 1u);   // round-to-nearest-even
    return (ushort_t)(r >> 16);
}
__device__ __forceinline__ void unpacknorm2(uint2 k, float a, float bb, float* v) {
    uint_t uu[2] = {k.x, k.y};
    #pragma unroll
    for (int j = 0; j < 2; ++j) {
        v[2*j]   = fmaxf(fmaf(__uint_as_float(uu[j] << 16),         a, bb), 0.f);
        v[2*j+1] = fmaxf(fmaf(__uint_as_float(uu[j] & 0xffff0000u), a, bb), 0.f);
    }
}

// ---- pack w1 + wproj into bf16 fragment order --------------------------------
__global__ __launch_bounds__(256) void k_prep(const float* __restrict__ w1,
                                              const float* __restrict__ wproj) {
    int idx = blockIdx.x*256 + threadIdx.x;        // 0..16383
    {
        int j = idx & 7, lane = (idx>>3) & 63, ot = (idx>>9) & 3;
        int ks = (idx>>11) & 1, wv = idx >> 12;
        int ln = lane & 15, q = lane >> 4;
        int o = wv*64 + ot*16 + ln, k = ks*32 + q*8 + j;
        g_wpack[idx] = f2bf(w1[o*CIN + k]);
    }
    {
        int j = idx & 7, lane = (idx>>3) & 63, ot = (idx>>9) & 3, kg = idx >> 11;
        int ln = lane & 15, q = lane >> 4;
        int o = ot*16 + ln, k = kg*32 + q*8 + j;
        g_wpack[16384 + idx] = f2bf(wproj[o*HID + k]);
    }
}

// ============ expand 1x1 via MFMA + fused per-channel stats1 partials =========
__global__ __launch_bounds__(256) void k_expand(const float* __restrict__ x,
                                                ushort_t* __restrict__ h1, int b0) {
    union SMem {
        ushort_t Bs[64*72];          // B[k][n], stride 72, rotated cols (18.4 KB)
        float    red[2][256][16];    // per-channel per-16lane partials (32 KB)
    };
    __shared__ SMem sm;
    const int tid = threadIdx.x;
    const int bb  = blockIdx.y, gb = b0 + bb;
    const int pos0 = blockIdx.x * 64;
    const int lane = tid & 63, wv = tid >> 6;
    const int q = lane >> 4, ln = lane & 15;

    bf16x8 af[2][4];
    #pragma unroll
    for (int ks = 0; ks < 2; ++ks)
        #pragma unroll
        for (int ot = 0; ot < 4; ++ot)
            af[ks][ot] = *(const bf16x8*)&g_wpack[(((wv*2+ks)*4+ot)<<9) + lane*8];

    #pragma unroll
    for (int i = 0; i < 4; ++i) {
        int lin = i*1024 + tid*4;
        int k = lin >> 6, n0 = lin & 63;
        float4 v = *(const float4*)&x[(size_t)(gb*CIN + k) * THW + pos0 + n0];
        ushort_t* d = &sm.Bs[k*72 + ((n0 + 16*((k>>3)&3)) & 63)];
        d[0] = f2bf(v.x); d[1] = f2bf(v.y); d[2] = f2bf(v.z); d[3] = f2bf(v.w);
    }
    __syncthreads();

    f32x4 acc[4][4];
    #pragma unroll
    for (int i = 0; i < 4; ++i)
        #pragma unroll
        for (int j = 0; j < 4; ++j)
            acc[i][j] = (f32x4){0.f,0.f,0.f,0.f};

    #pragma unroll
    for (int ks = 0; ks < 2; ++ks) {
        bf16x8 bfr[4];
        #pragma unroll
        for (int nt = 0; nt < 4; ++nt) {
            union { short s[8]; bf16x8 v; } bu;
            #pragma unroll
            for (int j = 0; j < 8; ++j) {
                int k = ks*32 + q*8 + j;
                int nn = (nt*16 + ln + 16*((k>>3)&3)) & 63;
                bu.s[j] = (short)sm.Bs[k*72 + nn];
            }
            bfr[nt] = bu.v;
        }
        #pragma unroll
        for (int ot = 0; ot < 4; ++ot)
            #pragma unroll
            for (int nt = 0; nt < 4; ++nt)
                acc[ot][nt] = __builtin_amdgcn_mfma_f32_16x16x32_bf16(
                    af[ks][ot], bfr[nt], acc[ot][nt], 0, 0, 0);
    }

    // epilogue: store + accumulate per-lane per-channel partial sums
    float sp_[16], ssp_[16];
    #pragma unroll
    for (int i = 0; i < 16; ++i) { sp_[i] = 0.f; ssp_[i] = 0.f; }

    #pragma unroll
    for (int ot = 0; ot < 4; ++ot)
        #pragma unroll
        for (int nt = 0; nt < 4; ++nt)
            #pragma unroll
            for (int r = 0; r < 4; ++r) {
                float vv = acc[ot][nt][r];
                int o = wv*64 + ot*16 + q*4 + r;
                int n = nt*16 + ln;
                h1[((size_t)bb*HID + o)*THW + pos0 + n] = f2bf(vv);
                sp_[ot*4+r] += vv;
                ssp_[ot*4+r] = fmaf(vv, vv, ssp_[ot*4+r]);
            }

    __syncthreads();           // all waves done reading Bs before union reuse
    #pragma unroll
    for (int i = 0; i < 16; ++i) {
        int o = wv*64 + (i>>2)*16 + q*4 + (i&3);
        sm.red[0][o][ln] = sp_[i];
        sm.red[1][o][ln] = ssp_[i];
    }
    __syncthreads();
    {
        float s = 0.f, ss = 0.f;
        #pragma unroll
        for (int l = 0; l < 16; ++l) {
            s  += sm.red[0][tid][l];
            ss += sm.red[1][tid][l];
        }
        size_t base = ((size_t)bb*1024 + blockIdx.x)*256 + tid;   // coalesced
        g_eps [base] = s;
        g_epss[base] = ss;
    }
}

// ---- stats1 transpose-reduction: g_eps [bb][posblk][ch] -> (a1,b1) per ch ----
// also writes the fixed stats for zero-forced TIM channels (32..63), since
// k_mid no longer launches blocks for them (grid compaction).
__global__ __launch_bounds__(256) void k_red() {
    const int tid = threadIdx.x;
    const int cg  = blockIdx.x;          // 0..15
    const int bb  = blockIdx.y;
    const int ch  = cg*16 + (tid & 15);
    const int pb0 = tid >> 4;            // 0..15
    const float* ps  = &g_eps [((size_t)bb*1024)*256];
    const float* pss = &g_epss[((size_t)bb*1024)*256];
    float s = 0.f, ss = 0.f;
    #pragma unroll 8
    for (int it = 0; it < 64; ++it) {
        int pb = it*16 + pb0;
        s  += ps [(size_t)pb*256 + ch];
        ss += pss[(size_t)pb*256 + ch];
    }
    __shared__ float rs[256], rss[256];
    rs[tid] = s; rss[tid] = ss;
    __syncthreads();
    if (tid < 16) {
        float st = 0.f, sst = 0.f;
        #pragma unroll
        for (int k = 0; k < 16; ++k) { st += rs[tid + 16*k]; sst += rss[tid + 16*k]; }
        float m = st * (1.f/THW);
        float v = sst * (1.f/THW) - m*m;
        float is = 1.f / sqrtf(v + EPS);
        int ch_ = cg*16 + tid;
        int bc = bb*HID + ch_;
        g_stats[SA1 + bc] = is;
        g_stats[SB1 + bc] = -m * is;
        if (ch_ >= 32 && ch_ < 64) {     // zero-forced TIM channels
            g_stats[SM3  + bc] = 0.f;
            g_stats[SIS3 + bc] = 1.f / sqrtf(EPS);
            g_stats[SSES + bc] = 0.f;
        }
    }
}

// ===== fused stage2+stage3: spatial dw3x3 -> IN -> relu -> temporal dw3 =======
// one block (1024 thr) per (bb, non-zero channel); dws output in keep[16] uint2.
// Dual-plane phase A: 4 LDS buffers, 2 planes staged+convolved per iteration ->
// 8 barriers instead of 16 (R13: 37% occupancy = barrier convoying with 16-wave
// blocks). T14 reg-staging keeps a full iteration of load slack. NO forced
// min-occupancy (R8: forcing causes spill). Stats1 precomputed by k_red.
__global__ __launch_bounds__(1024) void k_mid(const ushort_t* __restrict__ h1,
                                              const float* __restrict__ wdws,
                                              const float* __restrict__ wdwt,
                                              ushort_t* __restrict__ h3) {
    const int tid = threadIdx.x;                  // 0..1023
    const int oc  = blockIdx.x;                   // 0..223 compacted channel
    const int o   = (oc < 32) ? oc : oc + 32;     // skip zero channels 32..63
    const int bb  = blockIdx.y;
    const int bc  = bb*HID + o;
    const int wid = tid >> 6, lane = tid & 63;

    __shared__ float pl[4][66*67];                // 4 halo-padded norm'd planes
    __shared__ float ls[16], lss[16];
    __shared__ float sa, sb;

    const float a1 = g_stats[SA1 + bc];
    const float b1 = g_stats[SB1 + bc];

    // halo zero (all 4 buffers)
    if (tid < 66) {
        #pragma unroll
        for (int b = 0; b < 4; ++b) {
            pl[b][tid]         = 0.f;             // row 0
            pl[b][65*67 + tid] = 0.f;             // row 65
            pl[b][tid*67]      = 0.f;             // col 0
            pl[b][tid*67 + 65] = 0.f;             // col 65
        }
    }

    const int fut = (o < 32) ? 1 : 0;             // TIM future-shifted channel
    const int y   = tid >> 4;                     // 0..63
    const int x0  = (tid & 15) * 4;               // 0..60
    const ushort_t* chp = h1 + (size_t)bc * THW;
    const int lastp = fut ? (T_-2) : (T_-1);      // last plane with real input

    float wf[9];
    #pragma unroll
    for (int k = 0; k < 9; ++k) wf[k] = wdws[o*9 + k];

    // prologue: planes 0,1 staged; planes 2,3 loads in flight
    uint2 sreg[4];
    sreg[0] = *(const uint2*)(chp + (size_t)(0+fut)*HW_ + tid*4);
    sreg[1] = *(const uint2*)(chp + (size_t)(1+fut)*HW_ + tid*4);
    #pragma unroll
    for (int p = 0; p < 2; ++p) {
        float vv[4];
        unpacknorm2(sreg[p], a1, b1, vv);
        float* dst = &pl[p][(y+1)*67 + x0 + 1];
        #pragma unroll
        for (int i = 0; i < 4; ++i) dst[i] = vv[i];
    }
    sreg[2] = *(const uint2*)(chp + (size_t)(2+fut)*HW_ + tid*4);
    sreg[3] = *(const uint2*)(chp + (size_t)(3+fut)*HW_ + tid*4);
    __syncthreads();

    // ---- phase A: spatial 3x3 conv, 2 planes per barrier ---------------------
    uint2 keep[16];
    float s2 = 0.f, ss2 = 0.f;

    #pragma unroll
    for (int it = 0; it < 8; ++it) {
        // issue raw loads for planes 2it+4, 2it+5 (consumed next iteration)
        {
            int pA = 2*it + 4, pB = 2*it + 5;
            if (pA <= lastp)
                sreg[pA & 3] = *(const uint2*)(chp + (size_t)(pA+fut)*HW_ + tid*4);
            if (pB <= lastp)
                sreg[pB & 3] = *(const uint2*)(chp + (size_t)(pB+fut)*HW_ + tid*4);
        }
        // normalize + LDS-write planes 2it+2, 2it+3 (loaded one iteration ago)
        #pragma unroll
        for (int w = 0; w < 2; ++w) {
            int wp = 2*it + 2 + w;
            if (wp <= lastp) {
                float vv[4];
                unpacknorm2(sreg[wp & 3], a1, b1, vv);
                float* dst = &pl[wp & 3][(y+1)*67 + x0 + 1];
                #pragma unroll
                for (int i = 0; i < 4; ++i) dst[i] = vv[i];
            }
        }
        // convolve planes 2it, 2it+1
        #pragma unroll
        for (int cpi = 0; cpi < 2; ++cpi) {
            int t = 2*it + cpi;
            if (fut && t == T_-1) {
                keep[t] = (uint2){0u, 0u};        // TIM zero plane: dws out = 0
            } else {
                const float* plane = pl[t & 3];
                float v[3][6];
                #pragma unroll
                for (int dy = 0; dy < 3; ++dy) {
                    const float* rp = &plane[(y + dy)*67 + x0];
                    #pragma unroll
                    for (int j = 0; j < 6; ++j) v[dy][j] = rp[j];
                }
                uint_t outp[2];
                #pragma unroll
                for (int i2 = 0; i2 < 2; ++i2) {
                    float o0 = 0.f, o1 = 0.f;
                    #pragma unroll
                    for (int dy = 0; dy < 3; ++dy)
                        #pragma unroll
                        for (int dx = 0; dx < 3; ++dx) {
                            float w = wf[dy*3+dx];
                            o0 = fmaf(w, v[dy][2*i2 + dx],     o0);
                            o1 = fmaf(w, v[dy][2*i2 + 1 + dx], o1);
                        }
                    ushort_t u0 = f2bf(o0), u1 = f2bf(o1);
                    float r0 = bf2f(u0), r1 = bf2f(u1);
                    s2 += r0 + r1; ss2 = fmaf(r0, r0, fmaf(r1, r1, ss2));
                    outp[i2] = (uint_t)u0 | ((uint_t)u1 << 16);
                }
                keep[t].x = outp[0]; keep[t].y = outp[1];
            }
        }
        if (it < 7) __syncthreads();
    }

    // ---- phase B: stats2 block-reduce (never touches HBM) --------------------
    {
        float s = s2, ss = ss2;
        #pragma unroll
        for (int m = 32; m > 0; m >>= 1) {
            s  += __shfl_xor(s,  m);
            ss += __shfl_xor(ss, m);
        }
        if (lane == 0) { ls[wid] = s; lss[wid] = ss; }
        __syncthreads();
        if (tid == 0) {
            float st = 0.f, sst = 0.f;
            #pragma unroll
            for (int i = 0; i < 16; ++i) { st += ls[i]; sst += lss[i]; }
            float m = st * (1.f/THW);
            float v = sst * (1.f/THW) - m*m;
            float is = 1.f / sqrtf(v + EPS);
            sa = is; sb = -m * is;
        }
        __syncthreads();
    }
    const float a2 = sa, b2 = sb;
    // note: for fut channels keep[15]==0 -> unpacknorm2 gives relu(b2) == znorm

    // ---- phase C: temporal dw3 from registers, write h3, stats3 --------------
    const float w0 = wdwt[o*3+0], w1 = wdwt[o*3+1], w2 = wdwt[o*3+2];
    ushort_t* op = h3 + (size_t)bc * THW + tid*4;

    float p[4], c[4], n[4];
    #pragma unroll
    for (int i = 0; i < 4; ++i) p[i] = 0.f;
    unpacknorm2(keep[0], a2, b2, c);
    unpacknorm2(keep[1], a2, b2, n);

    float s3 = 0.f, ss3 = 0.f;
    #pragma unroll
    for (int t = 0; t < T_; ++t) {
        uint_t outp[2];
        #pragma unroll
        for (int i2 = 0; i2 < 2; ++i2) {
            float o0 = fmaf(w0, p[2*i2],   fmaf(w1, c[2*i2],   w2 * n[2*i2]));
            float o1 = fmaf(w0, p[2*i2+1], fmaf(w1, c[2*i2+1], w2 * n[2*i2+1]));
            ushort_t u0 = f2bf(o0), u1 = f2bf(o1);
            float r0 = bf2f(u0), r1 = bf2f(u1);
            s3 += r0 + r1; ss3 = fmaf(r0, r0, fmaf(r1, r1, ss3));
            outp[i2] = (uint_t)u0 | ((uint_t)u1 << 16);
        }
        uint2 r; r.x = outp[0]; r.y = outp[1];
        *(uint2*)(op + (size_t)t*HW_) = r;

        #pragma unroll
        for (int i = 0; i < 4; ++i) { p[i] = c[i]; c[i] = n[i]; }
        if (t + 2 < T_) unpacknorm2(keep[t+2], a2, b2, n);
        else {
            #pragma unroll
            for (int i = 0; i < 4; ++i) n[i] = 0.f;   // true conv zero-padding
        }
        keep[t] = r;                                   // reuse for SE-mean pass
    }

    {
        float s = s3, ss = ss3;
        #pragma unroll
        for (int m = 32; m > 0; m >>= 1) {
            s  += __shfl_xor(s,  m);
            ss += __shfl_xor(ss, m);
        }
        if (lane == 0) { ls[wid] = s; lss[wid] = ss; }
        __syncthreads();
        if (tid == 0) {
            float st = 0.f, sst = 0.f;
            #pragma unroll
            for (int i = 0; i < 16; ++i) { st += ls[i]; sst += lss[i]; }
            float m = st * (1.f/THW);
            float v = sst * (1.f/THW) - m*m;
            float is = 1.f / sqrtf(v + EPS);
            g_stats[SM3  + bc] = m;
            g_stats[SIS3 + bc] = is;
            sa = is; sb = -m * is;
        }
        __syncthreads();
    }

    // ---- phase D: SE mean of relu(norm3(h3)) from kept registers -------------
    const float a3 = sa, b3 = sb;
    float sse = 0.f;
    #pragma unroll
    for (int t = 0; t < T_; ++t) {
        uint_t uu[2] = {keep[t].x, keep[t].y};
        #pragma unroll
        for (int j = 0; j < 2; ++j) {
            sse += fmaxf(fmaf(__uint_as_float(uu[j] << 16),         a3, b3), 0.f);
            sse += fmaxf(fmaf(__uint_as_float(uu[j] & 0xffff0000u), a3, b3), 0.f);
        }
    }
    #pragma unroll
    for (int m = 32; m > 0; m >>= 1) sse += __shfl_xor(sse, m);
    if (lane == 0) ls[wid] = sse;
    __syncthreads();
    if (tid == 0) {
        float st = 0.f;
        #pragma unroll
        for (int i = 0; i < 16; ++i) st += ls[i];
        g_stats[SSES + bc] = st * (1.f/THW);
    }
}

// ------------ SE MLP -> fold sigmoid scale into proj's alpha/beta -------------
__global__ __launch_bounds__(256) void k_semlp(const float* __restrict__ wse1,
                                               const float* __restrict__ wse2) {
    __shared__ float mv[HID];
    __shared__ float y1[64];
    const int bb = blockIdx.x, tid = threadIdx.x;
    mv[tid] = g_stats[SSES + bb*HID + tid];
    __syncthreads();
    if (tid < 64) {
        float acc = 0.f;
        #pragma unroll 8
        for (int c = 0; c < HID; ++c) acc = fmaf(wse1[tid*HID + c], mv[c], acc);
        y1[tid] = fmaxf(acc, 0.f);
    }
    __syncthreads();
    float z = 0.f;
    #pragma unroll
    for (int c = 0; c < 64; ++c) z = fmaf(wse2[tid*64 + c], y1[c], z);
    float se = 1.f / (1.f + expf(-z));
    const int bc = bb*HID + tid;
    float al = g_stats[SIS3 + bc] * se;
    if (tid >= 32 && tid < 64) al = 0.f;   // zero-TIM channels: exact zero contribution
    g_stats[SAL + bc] = al;
    g_stats[SBE + bc] = -g_stats[SM3 + bc] * al;
}

// ============ proj 1x1 via MFMA (uint2 B-stage, alpha==0 skip) ================
// R5 version: no epilogue (R12 measured the partials machinery at net +15 us).
__global__ __launch_bounds__(256) void k_proj(const ushort_t* __restrict__ h3,
                                              float* __restrict__ proj) {
    __shared__ ushort_t Bs[64*136];      // B[klocal][n], stride 136, rotated cols
    const int tid = threadIdx.x;
    const int bb  = blockIdx.y;
    const int pos0 = blockIdx.x * 128;
    const int lane = tid & 63, wv = tid >> 6;
    const int q = lane >> 4, ln = lane & 15;

    f32x4 acc[4][2];
    #pragma unroll
    for (int i = 0; i < 4; ++i) {
        acc[i][0] = (f32x4){0.f,0.f,0.f,0.f};
        acc[i][1] = (f32x4){0.f,0.f,0.f,0.f};
    }

    for (int kc = 0; kc < 4; ++kc) {
        #pragma unroll
        for (int i = 0; i < 8; ++i) {
            int lin = i*1024 + tid*4;
            int kl = lin >> 7, n0 = lin & 127;
            int ch = bb*HID + kc*64 + kl;
            float al = g_stats[SAL + ch], be = g_stats[SBE + ch];
            ushort_t* d = &Bs[kl*136 + ((n0 + 16*((kl>>3)&7)) & 127)];
            if (al == 0.f) {                 // zero-forced TIM channels
                d[0] = 0; d[1] = 0; d[2] = 0; d[3] = 0;
            } else {
                uint2 u = *(const uint2*)&h3[(size_t)ch * THW + pos0 + n0];
                float f0 = __uint_as_float(u.x << 16);
                float f1 = __uint_as_float(u.x & 0xffff0000u);
                float f2 = __uint_as_float(u.y << 16);
                float f3 = __uint_as_float(u.y & 0xffff0000u);
                d[0] = f2bf(fmaxf(fmaf(f0, al, be), 0.f));
                d[1] = f2bf(fmaxf(fmaf(f1, al, be), 0.f));
                d[2] = f2bf(fmaxf(fmaf(f2, al, be), 0.f));
                d[3] = f2bf(fmaxf(fmaf(f3, al, be), 0.f));
            }
        }
        __syncthreads();

        #pragma unroll
        for (int ks = 0; ks < 2; ++ks) {
            int kg = kc*2 + ks;
            bf16x8 af[4];
            #pragma unroll
            for (int ot = 0; ot < 4; ++ot)
                af[ot] = *(const bf16x8*)&g_wpack[16384 + ((kg*4+ot)<<9) + lane*8];
            bf16x8 bfr[2];
            #pragma unroll
            for (int nt = 0; nt < 2; ++nt) {
                union { short s[8]; bf16x8 v; } bu;
                #pragma unroll
                for (int j = 0; j < 8; ++j) {
                    int kl = ks*32 + q*8 + j;
                    int nn = (wv*32 + nt*16 + ln + 16*((kl>>3)&7)) & 127;
                    bu.s[j] = (short)Bs[kl*136 + nn];
                }
                bfr[nt] = bu.v;
            }
            #pragma unroll
            for (int ot = 0; ot < 4; ++ot)
                #pragma unroll
                for (int nt = 0; nt < 2; ++nt)
                    acc[ot][nt] = __builtin_amdgcn_mfma_f32_16x16x32_bf16(
                        af[ot], bfr[nt], acc[ot][nt], 0, 0, 0);
        }
        __syncthreads();
    }

    #pragma unroll
    for (int ot = 0; ot < 4; ++ot)
        #pragma unroll
        for (int nt = 0; nt < 2; ++nt)
            #pragma unroll
            for (int r = 0; r < 4; ++r) {
                int o = ot*16 + q*4 + r;
                int n = wv*32 + nt*16 + ln;
                proj[((size_t)bb*COUT + o)*THW + pos0 + n] = acc[ot][nt][r];
            }
}

// ------------ final fused: proj stats + norm + shortcut + maxpool (R5) --------
__global__ __launch_bounds__(1024) void k_final(const float* __restrict__ proj,
                                                const float* __restrict__ x,
                                                float* __restrict__ out, int b0) {
    const int bo  = blockIdx.x;
    const int tid = threadIdx.x;
    const float* p = proj + (size_t)bo * THW;

    float s = 0.f, ss = 0.f;
    #pragma unroll
    for (int i = 0; i < THW/(1024*4); ++i) {
        float4 u = *(const float4*)(p + i*4096 + tid*4);
        s += u.x; ss = fmaf(u.x, u.x, ss);
        s += u.y; ss = fmaf(u.y, u.y, ss);
        s += u.z; ss = fmaf(u.z, u.z, ss);
        s += u.w; ss = fmaf(u.w, u.w, ss);
    }
    #pragma unroll
    for (int off = 32; off > 0; off >>= 1) {
        s  += __shfl_down(s,  off, 64);
        ss += __shfl_down(ss, off, 64);
    }
    __shared__ float ls[16], lss[16];
    __shared__ float sa, sb;
    int wid = tid >> 6, lane = tid & 63;
    if (lane == 0) { ls[wid] = s; lss[wid] = ss; }
    __syncthreads();
    if (tid == 0) {
        float st = 0.f, sst = 0.f;
        #pragma unroll
        for (int i = 0; i < 16; ++i) { st += ls[i]; sst += lss[i]; }
        float m = st * (1.f/THW);
        float v = sst * (1.f/THW) - m*m;
        float is = 1.f / sqrtf(v + EPS);
        sa = is; sb = -m * is;
    }
    __syncthreads();
    const float a = sa, bb = sb;

    const size_t gbase = (size_t)(b0*COUT + bo) * THW;
    float* op = out + (size_t)(b0*COUT + bo) * (T_*1024);
    #pragma unroll
    for (int i = 0; i < 16; ++i) {
        int idx = i*1024 + tid;
        int xx = idx & 31, yy = (idx >> 5) & 31, t = idx >> 10;
        float m = -3.4e38f;
        #pragma unroll
        for (int r = 0; r < 2; ++r) {
            size_t off = (size_t)t*HW_ + (size_t)(2*yy + r)*W_ + 2*xx;
            float2 p2 = *(const float2*)(p + off);
            float2 x2 = *(const float2*)(x + gbase + off);
            float v0 = fmaf(p2.x, a, bb) + x2.x;
            float v1 = fmaf(p2.y, a, bb) + x2.y;
            m = fmaxf(m, fmaxf(v0, v1));
        }
        op[idx] = m;
    }
}

extern "C" void kernel_launch(void* const* d_in, const int* in_sizes, int n_in,
                              void* d_out, int out_size, void* d_ws, size_t ws_size,
                              hipStream_t stream) {
    const float* x     = (const float*)d_in[0];
    const float* w1    = (const float*)d_in[1];
    const float* wdws  = (const float*)d_in[2];
    const float* wdwt  = (const float*)d_in[3];
    const float* wse1  = (const float*)d_in[4];
    const float* wse2  = (const float*)d_in[5];
    const float* wproj = (const float*)d_in[6];
    float* out = (float*)d_out;

    const size_t perb = 2ull * HID * THW * sizeof(ushort_t);   // 64 MB
    int nb = (ws_size >= 4*perb) ? 4 : (ws_size >= 2*perb) ? 2 : 1;

    k_prep<<<64, 256, 0, stream>>>(w1, wproj);

    for (int b0 = 0; b0 < B_; b0 += nb) {
        char* ws = (char*)d_ws;
        ushort_t* h1   = (ushort_t*)ws;
        ushort_t* h3   = h1;                                   // in-place per channel
        float*    proj = (float*)(ws + (size_t)nb * HID*THW*2);

        k_expand<<<dim3(THW/64, nb), 256, 0, stream>>>(x, h1, b0);
        k_red   <<<dim3(16, nb), 256, 0, stream>>>();
        k_mid   <<<dim3(224, nb), 1024, 0, stream>>>(h1, wdws, wdwt, h3);
        k_semlp <<<nb, 256, 0, stream>>>(wse1, wse2);
        k_proj  <<<dim3(THW/128, nb), 256, 0, stream>>>(h3, proj);
        k_final <<<nb*COUT, 1024, 0, stream>>>(proj, x, out, b0);
    }
}

// Round 20
// 347.217 us; speedup vs baseline: 1.0839x; 1.0115x over previous
//
#include <hip/hip_runtime.h>
#include <hip/hip_bf16.h>

#define B_   4
#define CIN  64
#define HID  256
#define COUT 64
#define T_   16
#define H_   64
#define W_   64
#define HW_  (H_*W_)       // 4096
#define THW  (T_*HW_)      // 65536
#define EPS  1e-5f

typedef unsigned short ushort_t;
typedef unsigned int   uint_t;
typedef short bf16x8 __attribute__((ext_vector_type(8)));
typedef float f32x4  __attribute__((ext_vector_type(4)));

// ---- stats in static device memory -------------------------------------------
#define SA1   0        // stats1 alpha (inv_sd) per (bb,ch)   <- k_red
#define SB1   1024     // stats1 beta  (-m*inv_sd)            <- k_red
#define SSES  6144     // SE mean per (bb,ch)                 <- k_mid / k_red
__device__ float g_stats[10240];
// per-(bb, pos-block, channel) partial sums from k_expand epilogue (stats1).
// layout [bb][posblk][ch]: k_expand's write (tid=ch) is COALESCED (the hot
// side, R5/R12-validated); k_red does the transpose-reduction (L2-hot).
__device__ float g_eps [4*1024*256];
__device__ float g_epss[4*1024*256];
// packed bf16 weights in MFMA fragment order: [0:16384) expand, [16384:32768) proj
__device__ ushort_t g_wpack[32768];
// per-bb proj weights pre-scaled by SE sigmoid (cols 32..63 zeroed) <- k_semlp
__device__ ushort_t g_wpackse[4*16384];

__device__ __forceinline__ float bf2f(ushort_t u) {
    return __uint_as_float(((uint_t)u) << 16);
}
__device__ __forceinline__ ushort_t f2bf(float f) {
    uint_t u = __float_as_uint(f);
    uint_t r = u + 0x7fffu + ((u >> 16) & 1u);   // round-to-nearest-even
    return (ushort_t)(r >> 16);
}
__device__ __forceinline__ void unpacknorm2(uint2 k, float a, float bb, float* v) {
    uint_t uu[2] = {k.x, k.y};
    #pragma unroll
    for (int j = 0; j < 2; ++j) {
        v[2*j]   = fmaxf(fmaf(__uint_as_float(uu[j] << 16),         a, bb), 0.f);
        v[2*j+1] = fmaxf(fmaf(__uint_as_float(uu[j] & 0xffff0000u), a, bb), 0.f);
    }
}

// ---- pack w1 + wproj into bf16 fragment order --------------------------------
__global__ __launch_bounds__(256) void k_prep(const float* __restrict__ w1,
                                              const float* __restrict__ wproj) {
    int idx = blockIdx.x*256 + threadIdx.x;        // 0..16383
    {
        int j = idx & 7, lane = (idx>>3) & 63, ot = (idx>>9) & 3;
        int ks = (idx>>11) & 1, wv = idx >> 12;
        int ln = lane & 15, q = lane >> 4;
        int o = wv*64 + ot*16 + ln, k = ks*32 + q*8 + j;
        g_wpack[idx] = f2bf(w1[o*CIN + k]);
    }
    {
        int j = idx & 7, lane = (idx>>3) & 63, ot = (idx>>9) & 3, kg = idx >> 11;
        int ln = lane & 15, q = lane >> 4;
        int o = ot*16 + ln, k = kg*32 + q*8 + j;
        g_wpack[16384 + idx] = f2bf(wproj[o*HID + k]);
    }
}

// ============ expand 1x1 via MFMA + fused per-channel stats1 partials =========
__global__ __launch_bounds__(256) void k_expand(const float* __restrict__ x,
                                                ushort_t* __restrict__ h1, int b0) {
    union SMem {
        ushort_t Bs[64*72];          // B[k][n], stride 72, rotated cols (18.4 KB)
        float    red[2][256][16];    // per-channel per-16lane partials (32 KB)
    };
    __shared__ SMem sm;
    const int tid = threadIdx.x;
    const int bb  = blockIdx.y, gb = b0 + bb;
    const int pos0 = blockIdx.x * 64;
    const int lane = tid & 63, wv = tid >> 6;
    const int q = lane >> 4, ln = lane & 15;

    bf16x8 af[2][4];
    #pragma unroll
    for (int ks = 0; ks < 2; ++ks)
        #pragma unroll
        for (int ot = 0; ot < 4; ++ot)
            af[ks][ot] = *(const bf16x8*)&g_wpack[(((wv*2+ks)*4+ot)<<9) + lane*8];

    #pragma unroll
    for (int i = 0; i < 4; ++i) {
        int lin = i*1024 + tid*4;
        int k = lin >> 6, n0 = lin & 63;
        float4 v = *(const float4*)&x[(size_t)(gb*CIN + k) * THW + pos0 + n0];
        ushort_t* d = &sm.Bs[k*72 + ((n0 + 16*((k>>3)&3)) & 63)];
        d[0] = f2bf(v.x); d[1] = f2bf(v.y); d[2] = f2bf(v.z); d[3] = f2bf(v.w);
    }
    __syncthreads();

    f32x4 acc[4][4];
    #pragma unroll
    for (int i = 0; i < 4; ++i)
        #pragma unroll
        for (int j = 0; j < 4; ++j)
            acc[i][j] = (f32x4){0.f,0.f,0.f,0.f};

    #pragma unroll
    for (int ks = 0; ks < 2; ++ks) {
        bf16x8 bfr[4];
        #pragma unroll
        for (int nt = 0; nt < 4; ++nt) {
            union { short s[8]; bf16x8 v; } bu;
            #pragma unroll
            for (int j = 0; j < 8; ++j) {
                int k = ks*32 + q*8 + j;
                int nn = (nt*16 + ln + 16*((k>>3)&3)) & 63;
                bu.s[j] = (short)sm.Bs[k*72 + nn];
            }
            bfr[nt] = bu.v;
        }
        #pragma unroll
        for (int ot = 0; ot < 4; ++ot)
            #pragma unroll
            for (int nt = 0; nt < 4; ++nt)
                acc[ot][nt] = __builtin_amdgcn_mfma_f32_16x16x32_bf16(
                    af[ks][ot], bfr[nt], acc[ot][nt], 0, 0, 0);
    }

    // epilogue: store + accumulate per-lane per-channel partial sums
    float sp_[16], ssp_[16];
    #pragma unroll
    for (int i = 0; i < 16; ++i) { sp_[i] = 0.f; ssp_[i] = 0.f; }

    #pragma unroll
    for (int ot = 0; ot < 4; ++ot)
        #pragma unroll
        for (int nt = 0; nt < 4; ++nt)
            #pragma unroll
            for (int r = 0; r < 4; ++r) {
                float vv = acc[ot][nt][r];
                int o = wv*64 + ot*16 + q*4 + r;
                int n = nt*16 + ln;
                h1[((size_t)bb*HID + o)*THW + pos0 + n] = f2bf(vv);
                sp_[ot*4+r] += vv;
                ssp_[ot*4+r] = fmaf(vv, vv, ssp_[ot*4+r]);
            }

    __syncthreads();           // all waves done reading Bs before union reuse
    #pragma unroll
    for (int i = 0; i < 16; ++i) {
        int o = wv*64 + (i>>2)*16 + q*4 + (i&3);
        sm.red[0][o][ln] = sp_[i];
        sm.red[1][o][ln] = ssp_[i];
    }
    __syncthreads();
    {
        float s = 0.f, ss = 0.f;
        #pragma unroll
        for (int l = 0; l < 16; ++l) {
            s  += sm.red[0][tid][l];
            ss += sm.red[1][tid][l];
        }
        size_t base = ((size_t)bb*1024 + blockIdx.x)*256 + tid;   // coalesced
        g_eps [base] = s;
        g_epss[base] = ss;
    }
}

// ---- stats1 transpose-reduction: g_eps [bb][posblk][ch] -> (a1,b1) per ch ----
// also writes SSES=0 for zero-forced TIM channels (k_mid skips them).
__global__ __launch_bounds__(256) void k_red() {
    const int tid = threadIdx.x;
    const int cg  = blockIdx.x;          // 0..15
    const int bb  = blockIdx.y;
    const int ch  = cg*16 + (tid & 15);
    const int pb0 = tid >> 4;            // 0..15
    const float* ps  = &g_eps [((size_t)bb*1024)*256];
    const float* pss = &g_epss[((size_t)bb*1024)*256];
    float s = 0.f, ss = 0.f;
    #pragma unroll 8
    for (int it = 0; it < 64; ++it) {
        int pb = it*16 + pb0;
        s  += ps [(size_t)pb*256 + ch];
        ss += pss[(size_t)pb*256 + ch];
    }
    __shared__ float rs[256], rss[256];
    rs[tid] = s; rss[tid] = ss;
    __syncthreads();
    if (tid < 16) {
        float st = 0.f, sst = 0.f;
        #pragma unroll
        for (int k = 0; k < 16; ++k) { st += rs[tid + 16*k]; sst += rss[tid + 16*k]; }
        float m = st * (1.f/THW);
        float v = sst * (1.f/THW) - m*m;
        float is = 1.f / sqrtf(v + EPS);
        int ch_ = cg*16 + tid;
        int bc = bb*HID + ch_;
        g_stats[SA1 + bc] = is;
        g_stats[SB1 + bc] = -m * is;
        if (ch_ >= 32 && ch_ < 64)       // zero-forced TIM channels
            g_stats[SSES + bc] = 0.f;
    }
}

// ===== fused stage2+stage3: spatial dw3x3 -> IN -> relu -> temporal dw3 =======
// one block (1024 thr) per (bb, non-zero channel); dws output in keep[16] uint2.
// Dual-plane phase A (R18-measured best). Phase D now stores h3 PRE-NORMALIZED:
// h3 = f2bf(relu(norm3(.))) so k_proj's staging is a pure bf16 copy (SE sigmoid
// folded into the weights by k_semlp). NO forced min-occupancy (R8: spill).
__global__ __launch_bounds__(1024) void k_mid(const ushort_t* __restrict__ h1,
                                              const float* __restrict__ wdws,
                                              const float* __restrict__ wdwt,
                                              ushort_t* __restrict__ h3) {
    const int tid = threadIdx.x;                  // 0..1023
    const int oc  = blockIdx.x;                   // 0..223 compacted channel
    const int o   = (oc < 32) ? oc : oc + 32;     // skip zero channels 32..63
    const int bb  = blockIdx.y;
    const int bc  = bb*HID + o;
    const int wid = tid >> 6, lane = tid & 63;

    __shared__ float pl[4][66*67];                // 4 halo-padded norm'd planes
    __shared__ float ls[16], lss[16];
    __shared__ float sa, sb;

    const float a1 = g_stats[SA1 + bc];
    const float b1 = g_stats[SB1 + bc];

    // halo zero (all 4 buffers)
    if (tid < 66) {
        #pragma unroll
        for (int b = 0; b < 4; ++b) {
            pl[b][tid]         = 0.f;             // row 0
            pl[b][65*67 + tid] = 0.f;             // row 65
            pl[b][tid*67]      = 0.f;             // col 0
            pl[b][tid*67 + 65] = 0.f;             // col 65
        }
    }

    const int fut = (o < 32) ? 1 : 0;             // TIM future-shifted channel
    const int y   = tid >> 4;                     // 0..63
    const int x0  = (tid & 15) * 4;               // 0..60
    const ushort_t* chp = h1 + (size_t)bc * THW;
    const int lastp = fut ? (T_-2) : (T_-1);      // last plane with real input

    float wf[9];
    #pragma unroll
    for (int k = 0; k < 9; ++k) wf[k] = wdws[o*9 + k];

    // prologue: planes 0,1 staged; planes 2,3 loads in flight
    uint2 sreg[4];
    sreg[0] = *(const uint2*)(chp + (size_t)(0+fut)*HW_ + tid*4);
    sreg[1] = *(const uint2*)(chp + (size_t)(1+fut)*HW_ + tid*4);
    #pragma unroll
    for (int p = 0; p < 2; ++p) {
        float vv[4];
        unpacknorm2(sreg[p], a1, b1, vv);
        float* dst = &pl[p][(y+1)*67 + x0 + 1];
        #pragma unroll
        for (int i = 0; i < 4; ++i) dst[i] = vv[i];
    }
    sreg[2] = *(const uint2*)(chp + (size_t)(2+fut)*HW_ + tid*4);
    sreg[3] = *(const uint2*)(chp + (size_t)(3+fut)*HW_ + tid*4);
    __syncthreads();

    // ---- phase A: spatial 3x3 conv, 2 planes per barrier ---------------------
    uint2 keep[16];
    float s2 = 0.f, ss2 = 0.f;

    #pragma unroll
    for (int it = 0; it < 8; ++it) {
        // issue raw loads for planes 2it+4, 2it+5 (consumed next iteration)
        {
            int pA = 2*it + 4, pB = 2*it + 5;
            if (pA <= lastp)
                sreg[pA & 3] = *(const uint2*)(chp + (size_t)(pA+fut)*HW_ + tid*4);
            if (pB <= lastp)
                sreg[pB & 3] = *(const uint2*)(chp + (size_t)(pB+fut)*HW_ + tid*4);
        }
        // normalize + LDS-write planes 2it+2, 2it+3 (loaded one iteration ago)
        #pragma unroll
        for (int w = 0; w < 2; ++w) {
            int wp = 2*it + 2 + w;
            if (wp <= lastp) {
                float vv[4];
                unpacknorm2(sreg[wp & 3], a1, b1, vv);
                float* dst = &pl[wp & 3][(y+1)*67 + x0 + 1];
                #pragma unroll
                for (int i = 0; i < 4; ++i) dst[i] = vv[i];
            }
        }
        // convolve planes 2it, 2it+1
        #pragma unroll
        for (int cpi = 0; cpi < 2; ++cpi) {
            int t = 2*it + cpi;
            if (fut && t == T_-1) {
                keep[t] = (uint2){0u, 0u};        // TIM zero plane: dws out = 0
            } else {
                const float* plane = pl[t & 3];
                float v[3][6];
                #pragma unroll
                for (int dy = 0; dy < 3; ++dy) {
                    const float* rp = &plane[(y + dy)*67 + x0];
                    #pragma unroll
                    for (int j = 0; j < 6; ++j) v[dy][j] = rp[j];
                }
                uint_t outp[2];
                #pragma unroll
                for (int i2 = 0; i2 < 2; ++i2) {
                    float o0 = 0.f, o1 = 0.f;
                    #pragma unroll
                    for (int dy = 0; dy < 3; ++dy)
                        #pragma unroll
                        for (int dx = 0; dx < 3; ++dx) {
                            float w = wf[dy*3+dx];
                            o0 = fmaf(w, v[dy][2*i2 + dx],     o0);
                            o1 = fmaf(w, v[dy][2*i2 + 1 + dx], o1);
                        }
                    ushort_t u0 = f2bf(o0), u1 = f2bf(o1);
                    float r0 = bf2f(u0), r1 = bf2f(u1);
                    s2 += r0 + r1; ss2 = fmaf(r0, r0, fmaf(r1, r1, ss2));
                    outp[i2] = (uint_t)u0 | ((uint_t)u1 << 16);
                }
                keep[t].x = outp[0]; keep[t].y = outp[1];
            }
        }
        if (it < 7) __syncthreads();
    }

    // ---- phase B: stats2 block-reduce (never touches HBM) --------------------
    {
        float s = s2, ss = ss2;
        #pragma unroll
        for (int m = 32; m > 0; m >>= 1) {
            s  += __shfl_xor(s,  m);
            ss += __shfl_xor(ss, m);
        }
        if (lane == 0) { ls[wid] = s; lss[wid] = ss; }
        __syncthreads();
        if (tid == 0) {
            float st = 0.f, sst = 0.f;
            #pragma unroll
            for (int i = 0; i < 16; ++i) { st += ls[i]; sst += lss[i]; }
            float m = st * (1.f/THW);
            float v = sst * (1.f/THW) - m*m;
            float is = 1.f / sqrtf(v + EPS);
            sa = is; sb = -m * is;
        }
        __syncthreads();
    }
    const float a2 = sa, b2 = sb;
    // note: for fut channels keep[15]==0 -> unpacknorm2 gives relu(b2) == znorm

    // ---- phase C: temporal dw3 from registers (outputs stay in keep[]) -------
    const float w0 = wdwt[o*3+0], w1 = wdwt[o*3+1], w2 = wdwt[o*3+2];

    float p[4], c[4], n[4];
    #pragma unroll
    for (int i = 0; i < 4; ++i) p[i] = 0.f;
    unpacknorm2(keep[0], a2, b2, c);
    unpacknorm2(keep[1], a2, b2, n);

    float s3 = 0.f, ss3 = 0.f;
    #pragma unroll
    for (int t = 0; t < T_; ++t) {
        uint_t outp[2];
        #pragma unroll
        for (int i2 = 0; i2 < 2; ++i2) {
            float o0 = fmaf(w0, p[2*i2],   fmaf(w1, c[2*i2],   w2 * n[2*i2]));
            float o1 = fmaf(w0, p[2*i2+1], fmaf(w1, c[2*i2+1], w2 * n[2*i2+1]));
            ushort_t u0 = f2bf(o0), u1 = f2bf(o1);
            float r0 = bf2f(u0), r1 = bf2f(u1);
            s3 += r0 + r1; ss3 = fmaf(r0, r0, fmaf(r1, r1, ss3));
            outp[i2] = (uint_t)u0 | ((uint_t)u1 << 16);
        }
        uint2 r; r.x = outp[0]; r.y = outp[1];

        #pragma unroll
        for (int i = 0; i < 4; ++i) { p[i] = c[i]; c[i] = n[i]; }
        if (t + 2 < T_) unpacknorm2(keep[t+2], a2, b2, n);
        else {
            #pragma unroll
            for (int i = 0; i < 4; ++i) n[i] = 0.f;   // true conv zero-padding
        }
        keep[t] = r;                                   // raw temporal output
    }

    {
        float s = s3, ss = ss3;
        #pragma unroll
        for (int m = 32; m > 0; m >>= 1) {
            s  += __shfl_xor(s,  m);
            ss += __shfl_xor(ss, m);
        }
        if (lane == 0) { ls[wid] = s; lss[wid] = ss; }
        __syncthreads();
        if (tid == 0) {
            float st = 0.f, sst = 0.f;
            #pragma unroll
            for (int i = 0; i < 16; ++i) { st += ls[i]; sst += lss[i]; }
            float m = st * (1.f/THW);
            float v = sst * (1.f/THW) - m*m;
            float is = 1.f / sqrtf(v + EPS);
            sa = is; sb = -m * is;
        }
        __syncthreads();
    }

    // ---- phase D: write h3 = relu(norm3(.)) bf16 + SE mean -------------------
    const float a3 = sa, b3 = sb;
    ushort_t* op = h3 + (size_t)bc * THW + tid*4;
    float sse = 0.f;
    #pragma unroll
    for (int t = 0; t < T_; ++t) {
        float vv[4];
        unpacknorm2(keep[t], a3, b3, vv);
        sse += vv[0] + vv[1] + vv[2] + vv[3];
        uint_t o0 = (uint_t)f2bf(vv[0]) | ((uint_t)f2bf(vv[1]) << 16);
        uint_t o1 = (uint_t)f2bf(vv[2]) | ((uint_t)f2bf(vv[3]) << 16);
        uint2 r; r.x = o0; r.y = o1;
        *(uint2*)(op + (size_t)t*HW_) = r;
    }
    #pragma unroll
    for (int m = 32; m > 0; m >>= 1) sse += __shfl_xor(sse, m);
    if (lane == 0) ls[wid] = sse;
    __syncthreads();
    if (tid == 0) {
        float st = 0.f;
        #pragma unroll
        for (int i = 0; i < 16; ++i) st += ls[i];
        g_stats[SSES + bc] = st * (1.f/THW);
    }
}

// ------------ SE MLP -> scale proj weights by sigmoid (per-bb buffer) ---------
__global__ __launch_bounds__(256) void k_semlp(const float* __restrict__ wse1,
                                               const float* __restrict__ wse2) {
    __shared__ float mv[HID];
    __shared__ float y1[64];
    __shared__ float sh_se[HID];
    const int bb = blockIdx.x, tid = threadIdx.x;
    mv[tid] = g_stats[SSES + bb*HID + tid];
    __syncthreads();
    if (tid < 64) {
        float acc = 0.f;
        #pragma unroll 8
        for (int c = 0; c < HID; ++c) acc = fmaf(wse1[tid*HID + c], mv[c], acc);
        y1[tid] = fmaxf(acc, 0.f);
    }
    __syncthreads();
    float z = 0.f;
    #pragma unroll
    for (int c = 0; c < 64; ++c) z = fmaf(wse2[tid*64 + c], y1[c], z);
    float se = 1.f / (1.f + expf(-z));
    sh_se[tid] = (tid >= 32 && tid < 64) ? 0.f : se;  // zero-TIM cols -> 0
    __syncthreads();
    // scale proj weights into per-bb buffer (w' = w * se[k])
    #pragma unroll 8
    for (int i = 0; i < 64; ++i) {
        int idx = i*256 + tid;                    // coalesced
        int j = idx & 7, lane = (idx>>3) & 63, kg = idx >> 11;
        int k = kg*32 + (lane>>4)*8 + j;
        g_wpackse[bb*16384 + idx] = f2bf(bf2f(g_wpack[16384 + idx]) * sh_se[k]);
    }
}

// ============ proj 1x1 via MFMA — staging is a PURE bf16 copy =================
// h3 already holds relu(norm3(.)); SE is folded into g_wpackse (zero cols for
// TIM channels kill their garbage activations exactly).
__global__ __launch_bounds__(256) void k_proj(const ushort_t* __restrict__ h3,
                                              float* __restrict__ proj) {
    __shared__ ushort_t Bs[64*136];      // B[klocal][n], stride 136, rotated cols
    const int tid = threadIdx.x;
    const int bb  = blockIdx.y;
    const int pos0 = blockIdx.x * 128;
    const int lane = tid & 63, wv = tid >> 6;
    const int q = lane >> 4, ln = lane & 15;

    f32x4 acc[4][2];
    #pragma unroll
    for (int i = 0; i < 4; ++i) {
        acc[i][0] = (f32x4){0.f,0.f,0.f,0.f};
        acc[i][1] = (f32x4){0.f,0.f,0.f,0.f};
    }

    for (int kc = 0; kc < 4; ++kc) {
        #pragma unroll
        for (int i = 0; i < 8; ++i) {
            int lin = i*1024 + tid*4;
            int kl = lin >> 7, n0 = lin & 127;
            int ch = bb*HID + kc*64 + kl;
            uint2 u = *(const uint2*)&h3[(size_t)ch * THW + pos0 + n0];
            ushort_t* d = &Bs[kl*136 + ((n0 + 16*((kl>>3)&7)) & 127)];
            d[0] = (ushort_t)(u.x & 0xffffu);
            d[1] = (ushort_t)(u.x >> 16);
            d[2] = (ushort_t)(u.y & 0xffffu);
            d[3] = (ushort_t)(u.y >> 16);
        }
        __syncthreads();

        #pragma unroll
        for (int ks = 0; ks < 2; ++ks) {
            int kg = kc*2 + ks;
            bf16x8 af[4];
            #pragma unroll
            for (int ot = 0; ot < 4; ++ot)
                af[ot] = *(const bf16x8*)&g_wpackse[bb*16384 + ((kg*4+ot)<<9) + lane*8];
            bf16x8 bfr[2];
            #pragma unroll
            for (int nt = 0; nt < 2; ++nt) {
                union { short s[8]; bf16x8 v; } bu;
                #pragma unroll
                for (int j = 0; j < 8; ++j) {
                    int kl = ks*32 + q*8 + j;
                    int nn = (wv*32 + nt*16 + ln + 16*((kl>>3)&7)) & 127;
                    bu.s[j] = (short)Bs[kl*136 + nn];
                }
                bfr[nt] = bu.v;
            }
            #pragma unroll
            for (int ot = 0; ot < 4; ++ot)
                #pragma unroll
                for (int nt = 0; nt < 2; ++nt)
                    acc[ot][nt] = __builtin_amdgcn_mfma_f32_16x16x32_bf16(
                        af[ot], bfr[nt], acc[ot][nt], 0, 0, 0);
        }
        __syncthreads();
    }

    #pragma unroll
    for (int ot = 0; ot < 4; ++ot)
        #pragma unroll
        for (int nt = 0; nt < 2; ++nt)
            #pragma unroll
            for (int r = 0; r < 4; ++r) {
                int o = ot*16 + q*4 + r;
                int n = wv*32 + nt*16 + ln;
                proj[((size_t)bb*COUT + o)*THW + pos0 + n] = acc[ot][nt][r];
            }
}

// ------------ final fused: proj stats + norm + shortcut + maxpool (R5) --------
__global__ __launch_bounds__(1024) void k_final(const float* __restrict__ proj,
                                                const float* __restrict__ x,
                                                float* __restrict__ out, int b0) {
    const int bo  = blockIdx.x;
    const int tid = threadIdx.x;
    const float* p = proj + (size_t)bo * THW;

    float s = 0.f, ss = 0.f;
    #pragma unroll
    for (int i = 0; i < THW/(1024*4); ++i) {
        float4 u = *(const float4*)(p + i*4096 + tid*4);
        s += u.x; ss = fmaf(u.x, u.x, ss);
        s += u.y; ss = fmaf(u.y, u.y, ss);
        s += u.z; ss = fmaf(u.z, u.z, ss);
        s += u.w; ss = fmaf(u.w, u.w, ss);
    }
    #pragma unroll
    for (int off = 32; off > 0; off >>= 1) {
        s  += __shfl_down(s,  off, 64);
        ss += __shfl_down(ss, off, 64);
    }
    __shared__ float ls[16], lss[16];
    __shared__ float sa, sb;
    int wid = tid >> 6, lane = tid & 63;
    if (lane == 0) { ls[wid] = s; lss[wid] = ss; }
    __syncthreads();
    if (tid == 0) {
        float st = 0.f, sst = 0.f;
        #pragma unroll
        for (int i = 0; i < 16; ++i) { st += ls[i]; sst += lss[i]; }
        float m = st * (1.f/THW);
        float v = sst * (1.f/THW) - m*m;
        float is = 1.f / sqrtf(v + EPS);
        sa = is; sb = -m * is;
    }
    __syncthreads();
    const float a = sa, bb = sb;

    const size_t gbase = (size_t)(b0*COUT + bo) * THW;
    float* op = out + (size_t)(b0*COUT + bo) * (T_*1024);
    #pragma unroll
    for (int i = 0; i < 16; ++i) {
        int idx = i*1024 + tid;
        int xx = idx & 31, yy = (idx >> 5) & 31, t = idx >> 10;
        float m = -3.4e38f;
        #pragma unroll
        for (int r = 0; r < 2; ++r) {
            size_t off = (size_t)t*HW_ + (size_t)(2*yy + r)*W_ + 2*xx;
            float2 p2 = *(const float2*)(p + off);
            float2 x2 = *(const float2*)(x + gbase + off);
            float v0 = fmaf(p2.x, a, bb) + x2.x;
            float v1 = fmaf(p2.y, a, bb) + x2.y;
            m = fmaxf(m, fmaxf(v0, v1));
        }
        op[idx] = m;
    }
}

extern "C" void kernel_launch(void* const* d_in, const int* in_sizes, int n_in,
                              void* d_out, int out_size, void* d_ws, size_t ws_size,
                              hipStream_t stream) {
    const float* x     = (const float*)d_in[0];
    const float* w1    = (const float*)d_in[1];
    const float* wdws  = (const float*)d_in[2];
    const float* wdwt  = (const float*)d_in[3];
    const float* wse1  = (const float*)d_in[4];
    const float* wse2  = (const float*)d_in[5];
    const float* wproj = (const float*)d_in[6];
    float* out = (float*)d_out;

    const size_t perb = 2ull * HID * THW * sizeof(ushort_t);   // 64 MB
    int nb = (ws_size >= 4*perb) ? 4 : (ws_size >= 2*perb) ? 2 : 1;

    k_prep<<<64, 256, 0, stream>>>(w1, wproj);

    for (int b0 = 0; b0 < B_; b0 += nb) {
        char* ws = (char*)d_ws;
        ushort_t* h1   = (ushort_t*)ws;
        ushort_t* h3   = h1;                                   // in-place per channel
        float*    proj = (float*)(ws + (size_t)nb * HID*THW*2);

        k_expand<<<dim3(THW/64, nb), 256, 0, stream>>>(x, h1, b0);
        k_red   <<<dim3(16, nb), 256, 0, stream>>>();
        k_mid   <<<dim3(224, nb), 1024, 0, stream>>>(h1, wdws, wdwt, h3);
        k_semlp <<<nb, 256, 0, stream>>>(wse1, wse2);
        k_proj  <<<dim3(THW/128, nb), 256, 0, stream>>>(h3, proj);
        k_final <<<nb*COUT, 1024, 0, stream>>>(proj, x, out, b0);
    }
}

// Round 22
// 328.745 us; speedup vs baseline: 1.1448x; 1.0562x over previous
//
#include <hip/hip_runtime.h>
#include <hip/hip_bf16.h>

#define B_   4
#define CIN  64
#define HID  256
#define COUT 64
#define T_   16
#define H_   64
#define W_   64
#define HW_  (H_*W_)       // 4096
#define THW  (T_*HW_)      // 65536
#define EPS  1e-5f

typedef unsigned short ushort_t;
typedef unsigned int   uint_t;
typedef short bf16x8 __attribute__((ext_vector_type(8)));
typedef float f32x4  __attribute__((ext_vector_type(4)));

// ---- stats in static device memory -------------------------------------------
#define SA1   0        // stats1 alpha (inv_sd) per (bb,ch)   <- k_red
#define SB1   1024     // stats1 beta  (-m*inv_sd)            <- k_red
#define SSES  6144     // SE mean per (bb,ch)                 <- k_mid / k_red
__device__ float g_stats[10240];
// per-(bb, pos-block, channel) partial sums from k_expand epilogue (stats1).
__device__ float g_eps [4*1024*256];
__device__ float g_epss[4*1024*256];
// packed bf16 weights in MFMA fragment order: [0:16384) expand, [16384:32768) proj
__device__ ushort_t g_wpack[32768];
// per-bb proj weights pre-scaled by SE sigmoid (cols 32..63 zeroed) <- k_semlp
__device__ ushort_t g_wpackse[4*16384];

__device__ __forceinline__ float bf2f(ushort_t u) {
    return __uint_as_float(((uint_t)u) << 16);
}
__device__ __forceinline__ ushort_t f2bf(float f) {
    uint_t u = __float_as_uint(f);
    uint_t r = u + 0x7fffu + ((u >> 16) & 1u);   // round-to-nearest-even
    return (ushort_t)(r >> 16);
}
__device__ __forceinline__ void unpacknorm2(uint2 k, float a, float bb, float* v) {
    uint_t uu[2] = {k.x, k.y};
    #pragma unroll
    for (int j = 0; j < 2; ++j) {
        v[2*j]   = fmaxf(fmaf(__uint_as_float(uu[j] << 16),         a, bb), 0.f);
        v[2*j+1] = fmaxf(fmaf(__uint_as_float(uu[j] & 0xffff0000u), a, bb), 0.f);
    }
}

// ---- pack w1 + wproj into bf16 fragment order --------------------------------
__global__ __launch_bounds__(256) void k_prep(const float* __restrict__ w1,
                                              const float* __restrict__ wproj) {
    int idx = blockIdx.x*256 + threadIdx.x;        // 0..16383
    {
        int j = idx & 7, lane = (idx>>3) & 63, ot = (idx>>9) & 3;
        int ks = (idx>>11) & 1, wv = idx >> 12;
        int ln = lane & 15, q = lane >> 4;
        int o = wv*64 + ot*16 + ln, k = ks*32 + q*8 + j;
        g_wpack[idx] = f2bf(w1[o*CIN + k]);
    }
    {
        int j = idx & 7, lane = (idx>>3) & 63, ot = (idx>>9) & 3, kg = idx >> 11;
        int ln = lane & 15, q = lane >> 4;
        int o = ot*16 + ln, k = kg*32 + q*8 + j;
        g_wpack[16384 + idx] = f2bf(wproj[o*HID + k]);
    }
}

// ============ expand 1x1 via MFMA + fused per-channel stats1 partials =========
__global__ __launch_bounds__(256) void k_expand(const float* __restrict__ x,
                                                ushort_t* __restrict__ h1, int b0) {
    union SMem {
        ushort_t Bs[64*72];          // B[k][n], stride 72, rotated cols (18.4 KB)
        float    red[2][256][16];    // per-channel per-16lane partials (32 KB)
    };
    __shared__ SMem sm;
    const int tid = threadIdx.x;
    const int bb  = blockIdx.y, gb = b0 + bb;
    const int pos0 = blockIdx.x * 64;
    const int lane = tid & 63, wv = tid >> 6;
    const int q = lane >> 4, ln = lane & 15;

    bf16x8 af[2][4];
    #pragma unroll
    for (int ks = 0; ks < 2; ++ks)
        #pragma unroll
        for (int ot = 0; ot < 4; ++ot)
            af[ks][ot] = *(const bf16x8*)&g_wpack[(((wv*2+ks)*4+ot)<<9) + lane*8];

    #pragma unroll
    for (int i = 0; i < 4; ++i) {
        int lin = i*1024 + tid*4;
        int k = lin >> 6, n0 = lin & 63;
        float4 v = *(const float4*)&x[(size_t)(gb*CIN + k) * THW + pos0 + n0];
        ushort_t* d = &sm.Bs[k*72 + ((n0 + 16*((k>>3)&3)) & 63)];
        d[0] = f2bf(v.x); d[1] = f2bf(v.y); d[2] = f2bf(v.z); d[3] = f2bf(v.w);
    }
    __syncthreads();

    f32x4 acc[4][4];
    #pragma unroll
    for (int i = 0; i < 4; ++i)
        #pragma unroll
        for (int j = 0; j < 4; ++j)
            acc[i][j] = (f32x4){0.f,0.f,0.f,0.f};

    #pragma unroll
    for (int ks = 0; ks < 2; ++ks) {
        bf16x8 bfr[4];
        #pragma unroll
        for (int nt = 0; nt < 4; ++nt) {
            union { short s[8]; bf16x8 v; } bu;
            #pragma unroll
            for (int j = 0; j < 8; ++j) {
                int k = ks*32 + q*8 + j;
                int nn = (nt*16 + ln + 16*((k>>3)&3)) & 63;
                bu.s[j] = (short)sm.Bs[k*72 + nn];
            }
            bfr[nt] = bu.v;
        }
        #pragma unroll
        for (int ot = 0; ot < 4; ++ot)
            #pragma unroll
            for (int nt = 0; nt < 4; ++nt)
                acc[ot][nt] = __builtin_amdgcn_mfma_f32_16x16x32_bf16(
                    af[ks][ot], bfr[nt], acc[ot][nt], 0, 0, 0);
    }

    // epilogue: store + accumulate per-lane per-channel partial sums
    float sp_[16], ssp_[16];
    #pragma unroll
    for (int i = 0; i < 16; ++i) { sp_[i] = 0.f; ssp_[i] = 0.f; }

    #pragma unroll
    for (int ot = 0; ot < 4; ++ot)
        #pragma unroll
        for (int nt = 0; nt < 4; ++nt)
            #pragma unroll
            for (int r = 0; r < 4; ++r) {
                float vv = acc[ot][nt][r];
                int o = wv*64 + ot*16 + q*4 + r;
                int n = nt*16 + ln;
                h1[((size_t)bb*HID + o)*THW + pos0 + n] = f2bf(vv);
                sp_[ot*4+r] += vv;
                ssp_[ot*4+r] = fmaf(vv, vv, ssp_[ot*4+r]);
            }

    __syncthreads();           // all waves done reading Bs before union reuse
    #pragma unroll
    for (int i = 0; i < 16; ++i) {
        int o = wv*64 + (i>>2)*16 + q*4 + (i&3);
        sm.red[0][o][ln] = sp_[i];
        sm.red[1][o][ln] = ssp_[i];
    }
    __syncthreads();
    {
        float s = 0.f, ss = 0.f;
        #pragma unroll
        for (int l = 0; l < 16; ++l) {
            s  += sm.red[0][tid][l];
            ss += sm.red[1][tid][l];
        }
        size_t base = ((size_t)bb*1024 + blockIdx.x)*256 + tid;   // coalesced
        g_eps [base] = s;
        g_epss[base] = ss;
    }
}

// ---- stats1 transpose-reduction: g_eps [bb][posblk][ch] -> (a1,b1) per ch ----
__global__ __launch_bounds__(256) void k_red() {
    const int tid = threadIdx.x;
    const int cg  = blockIdx.x;          // 0..15
    const int bb  = blockIdx.y;
    const int ch  = cg*16 + (tid & 15);
    const int pb0 = tid >> 4;            // 0..15
    const float* ps  = &g_eps [((size_t)bb*1024)*256];
    const float* pss = &g_epss[((size_t)bb*1024)*256];
    float s = 0.f, ss = 0.f;
    #pragma unroll 8
    for (int it = 0; it < 64; ++it) {
        int pb = it*16 + pb0;
        s  += ps [(size_t)pb*256 + ch];
        ss += pss[(size_t)pb*256 + ch];
    }
    __shared__ float rs[256], rss[256];
    rs[tid] = s; rss[tid] = ss;
    __syncthreads();
    if (tid < 16) {
        float st = 0.f, sst = 0.f;
        #pragma unroll
        for (int k = 0; k < 16; ++k) { st += rs[tid + 16*k]; sst += rss[tid + 16*k]; }
        float m = st * (1.f/THW);
        float v = sst * (1.f/THW) - m*m;
        float is = 1.f / sqrtf(v + EPS);
        int ch_ = cg*16 + tid;
        int bc = bb*HID + ch_;
        g_stats[SA1 + bc] = is;
        g_stats[SB1 + bc] = -m * is;
        if (ch_ >= 32 && ch_ < 64)       // zero-forced TIM channels
            g_stats[SSES + bc] = 0.f;
    }
}

// ===== fused stage2+stage3: spatial dw3x3 -> IN -> relu -> temporal dw3 =======
// Dual-plane phase A (R18). Phase D stores h3 pre-normalized (R20). Stats in
// phases A/C accumulate UNROUNDED f32 conv outputs (closer to f32 ref,
// fewer VALU ops); keep[] packing unchanged.
__global__ __launch_bounds__(1024) void k_mid(const ushort_t* __restrict__ h1,
                                              const float* __restrict__ wdws,
                                              const float* __restrict__ wdwt,
                                              ushort_t* __restrict__ h3) {
    const int tid = threadIdx.x;                  // 0..1023
    const int oc  = blockIdx.x;                   // 0..223 compacted channel
    const int o   = (oc < 32) ? oc : oc + 32;     // skip zero channels 32..63
    const int bb  = blockIdx.y;
    const int bc  = bb*HID + o;
    const int wid = tid >> 6, lane = tid & 63;

    __shared__ float pl[4][66*67];                // 4 halo-padded norm'd planes
    __shared__ float ls[16], lss[16];
    __shared__ float sa, sb;

    const float a1 = g_stats[SA1 + bc];
    const float b1 = g_stats[SB1 + bc];

    // halo zero (all 4 buffers)
    if (tid < 66) {
        #pragma unroll
        for (int b = 0; b < 4; ++b) {
            pl[b][tid]         = 0.f;             // row 0
            pl[b][65*67 + tid] = 0.f;             // row 65
            pl[b][tid*67]      = 0.f;             // col 0
            pl[b][tid*67 + 65] = 0.f;             // col 65
        }
    }

    const int fut = (o < 32) ? 1 : 0;             // TIM future-shifted channel
    const int y   = tid >> 4;                     // 0..63
    const int x0  = (tid & 15) * 4;               // 0..60
    const ushort_t* chp = h1 + (size_t)bc * THW;
    const int lastp = fut ? (T_-2) : (T_-1);      // last plane with real input

    float wf[9];
    #pragma unroll
    for (int k = 0; k < 9; ++k) wf[k] = wdws[o*9 + k];

    // prologue: planes 0,1 staged; planes 2,3 loads in flight
    uint2 sreg[4];
    sreg[0] = *(const uint2*)(chp + (size_t)(0+fut)*HW_ + tid*4);
    sreg[1] = *(const uint2*)(chp + (size_t)(1+fut)*HW_ + tid*4);
    #pragma unroll
    for (int p = 0; p < 2; ++p) {
        float vv[4];
        unpacknorm2(sreg[p], a1, b1, vv);
        float* dst = &pl[p][(y+1)*67 + x0 + 1];
        #pragma unroll
        for (int i = 0; i < 4; ++i) dst[i] = vv[i];
    }
    sreg[2] = *(const uint2*)(chp + (size_t)(2+fut)*HW_ + tid*4);
    sreg[3] = *(const uint2*)(chp + (size_t)(3+fut)*HW_ + tid*4);
    __syncthreads();

    // ---- phase A: spatial 3x3 conv, 2 planes per barrier ---------------------
    uint2 keep[16];
    float s2 = 0.f, ss2 = 0.f;

    #pragma unroll
    for (int it = 0; it < 8; ++it) {
        // issue raw loads for planes 2it+4, 2it+5 (consumed next iteration)
        {
            int pA = 2*it + 4, pB = 2*it + 5;
            if (pA <= lastp)
                sreg[pA & 3] = *(const uint2*)(chp + (size_t)(pA+fut)*HW_ + tid*4);
            if (pB <= lastp)
                sreg[pB & 3] = *(const uint2*)(chp + (size_t)(pB+fut)*HW_ + tid*4);
        }
        // normalize + LDS-write planes 2it+2, 2it+3 (loaded one iteration ago)
        #pragma unroll
        for (int w = 0; w < 2; ++w) {
            int wp = 2*it + 2 + w;
            if (wp <= lastp) {
                float vv[4];
                unpacknorm2(sreg[wp & 3], a1, b1, vv);
                float* dst = &pl[wp & 3][(y+1)*67 + x0 + 1];
                #pragma unroll
                for (int i = 0; i < 4; ++i) dst[i] = vv[i];
            }
        }
        // convolve planes 2it, 2it+1
        #pragma unroll
        for (int cpi = 0; cpi < 2; ++cpi) {
            int t = 2*it + cpi;
            if (fut && t == T_-1) {
                keep[t] = (uint2){0u, 0u};        // TIM zero plane: dws out = 0
            } else {
                const float* plane = pl[t & 3];
                float v[3][6];
                #pragma unroll
                for (int dy = 0; dy < 3; ++dy) {
                    const float* rp = &plane[(y + dy)*67 + x0];
                    #pragma unroll
                    for (int j = 0; j < 6; ++j) v[dy][j] = rp[j];
                }
                uint_t outp[2];
                #pragma unroll
                for (int i2 = 0; i2 < 2; ++i2) {
                    float o0 = 0.f, o1 = 0.f;
                    #pragma unroll
                    for (int dy = 0; dy < 3; ++dy)
                        #pragma unroll
                        for (int dx = 0; dx < 3; ++dx) {
                            float w = wf[dy*3+dx];
                            o0 = fmaf(w, v[dy][2*i2 + dx],     o0);
                            o1 = fmaf(w, v[dy][2*i2 + 1 + dx], o1);
                        }
                    s2 += o0 + o1; ss2 = fmaf(o0, o0, fmaf(o1, o1, ss2));
                    outp[i2] = (uint_t)f2bf(o0) | ((uint_t)f2bf(o1) << 16);
                }
                keep[t].x = outp[0]; keep[t].y = outp[1];
            }
        }
        if (it < 7) __syncthreads();
    }

    // ---- phase B: stats2 block-reduce (never touches HBM) --------------------
    {
        float s = s2, ss = ss2;
        #pragma unroll
        for (int m = 32; m > 0; m >>= 1) {
            s  += __shfl_xor(s,  m);
            ss += __shfl_xor(ss, m);
        }
        if (lane == 0) { ls[wid] = s; lss[wid] = ss; }
        __syncthreads();
        if (tid == 0) {
            float st = 0.f, sst = 0.f;
            #pragma unroll
            for (int i = 0; i < 16; ++i) { st += ls[i]; sst += lss[i]; }
            float m = st * (1.f/THW);
            float v = sst * (1.f/THW) - m*m;
            float is = 1.f / sqrtf(v + EPS);
            sa = is; sb = -m * is;
        }
        __syncthreads();
    }
    const float a2 = sa, b2 = sb;
    // note: for fut channels keep[15]==0 -> unpacknorm2 gives relu(b2) == znorm

    // ---- phase C: temporal dw3 from registers (outputs stay in keep[]) -------
    const float w0 = wdwt[o*3+0], w1 = wdwt[o*3+1], w2 = wdwt[o*3+2];

    float p[4], c[4], n[4];
    #pragma unroll
    for (int i = 0; i < 4; ++i) p[i] = 0.f;
    unpacknorm2(keep[0], a2, b2, c);
    unpacknorm2(keep[1], a2, b2, n);

    float s3 = 0.f, ss3 = 0.f;
    #pragma unroll
    for (int t = 0; t < T_; ++t) {
        uint_t outp[2];
        #pragma unroll
        for (int i2 = 0; i2 < 2; ++i2) {
            float o0 = fmaf(w0, p[2*i2],   fmaf(w1, c[2*i2],   w2 * n[2*i2]));
            float o1 = fmaf(w0, p[2*i2+1], fmaf(w1, c[2*i2+1], w2 * n[2*i2+1]));
            s3 += o0 + o1; ss3 = fmaf(o0, o0, fmaf(o1, o1, ss3));
            outp[i2] = (uint_t)f2bf(o0) | ((uint_t)f2bf(o1) << 16);
        }
        uint2 r; r.x = outp[0]; r.y = outp[1];

        #pragma unroll
        for (int i = 0; i < 4; ++i) { p[i] = c[i]; c[i] = n[i]; }
        if (t + 2 < T_) unpacknorm2(keep[t+2], a2, b2, n);
        else {
            #pragma unroll
            for (int i = 0; i < 4; ++i) n[i] = 0.f;   // true conv zero-padding
        }
        keep[t] = r;                                   // raw temporal output
    }

    {
        float s = s3, ss = ss3;
        #pragma unroll
        for (int m = 32; m > 0; m >>= 1) {
            s  += __shfl_xor(s,  m);
            ss += __shfl_xor(ss, m);
        }
        if (lane == 0) { ls[wid] = s; lss[wid] = ss; }
        __syncthreads();
        if (tid == 0) {
            float st = 0.f, sst = 0.f;
            #pragma unroll
            for (int i = 0; i < 16; ++i) { st += ls[i]; sst += lss[i]; }
            float m = st * (1.f/THW);
            float v = sst * (1.f/THW) - m*m;
            float is = 1.f / sqrtf(v + EPS);
            sa = is; sb = -m * is;
        }
        __syncthreads();
    }

    // ---- phase D: write h3 = relu(norm3(.)) bf16 + SE mean -------------------
    const float a3 = sa, b3 = sb;
    ushort_t* op = h3 + (size_t)bc * THW + tid*4;
    float sse = 0.f;
    #pragma unroll
    for (int t = 0; t < T_; ++t) {
        float vv[4];
        unpacknorm2(keep[t], a3, b3, vv);
        sse += vv[0] + vv[1] + vv[2] + vv[3];
        uint_t o0 = (uint_t)f2bf(vv[0]) | ((uint_t)f2bf(vv[1]) << 16);
        uint_t o1 = (uint_t)f2bf(vv[2]) | ((uint_t)f2bf(vv[3]) << 16);
        uint2 r; r.x = o0; r.y = o1;
        *(uint2*)(op + (size_t)t*HW_) = r;
    }
    #pragma unroll
    for (int m = 32; m > 0; m >>= 1) sse += __shfl_xor(sse, m);
    if (lane == 0) ls[wid] = sse;
    __syncthreads();
    if (tid == 0) {
        float st = 0.f;
        #pragma unroll
        for (int i = 0; i < 16; ++i) st += ls[i];
        g_stats[SSES + bc] = st * (1.f/THW);
    }
}

// ------------ SE MLP -> scale proj weights by sigmoid (per-bb buffer) ---------
__global__ __launch_bounds__(256) void k_semlp(const float* __restrict__ wse1,
                                               const float* __restrict__ wse2) {
    __shared__ float mv[HID];
    __shared__ float y1[64];
    __shared__ float sh_se[HID];
    const int bb = blockIdx.x, tid = threadIdx.x;
    mv[tid] = g_stats[SSES + bb*HID + tid];
    __syncthreads();
    if (tid < 64) {
        float acc = 0.f;
        #pragma unroll 8
        for (int c = 0; c < HID; ++c) acc = fmaf(wse1[tid*HID + c], mv[c], acc);
        y1[tid] = fmaxf(acc, 0.f);
    }
    __syncthreads();
    float z = 0.f;
    #pragma unroll
    for (int c = 0; c < 64; ++c) z = fmaf(wse2[tid*64 + c], y1[c], z);
    float se = 1.f / (1.f + expf(-z));
    sh_se[tid] = (tid >= 32 && tid < 64) ? 0.f : se;  // zero-TIM cols -> 0
    __syncthreads();
    // scale proj weights into per-bb buffer (w' = w * se[k])
    #pragma unroll 8
    for (int i = 0; i < 64; ++i) {
        int idx = i*256 + tid;                    // coalesced
        int j = idx & 7, lane = (idx>>3) & 63, kg = idx >> 11;
        int k = kg*32 + (lane>>4)*8 + j;
        g_wpackse[bb*16384 + idx] = f2bf(bf2f(g_wpack[16384 + idx]) * sh_se[k]);
    }
}

// ============ proj 1x1 via MFMA — bf16 output (halves proj traffic) ===========
__global__ __launch_bounds__(256) void k_proj(const ushort_t* __restrict__ h3,
                                              ushort_t* __restrict__ proj) {
    __shared__ ushort_t Bs[64*136];      // B[klocal][n], stride 136, rotated cols
    const int tid = threadIdx.x;
    const int bb  = blockIdx.y;
    const int pos0 = blockIdx.x * 128;
    const int lane = tid & 63, wv = tid >> 6;
    const int q = lane >> 4, ln = lane & 15;

    f32x4 acc[4][2];
    #pragma unroll
    for (int i = 0; i < 4; ++i) {
        acc[i][0] = (f32x4){0.f,0.f,0.f,0.f};
        acc[i][1] = (f32x4){0.f,0.f,0.f,0.f};
    }

    for (int kc = 0; kc < 4; ++kc) {
        #pragma unroll
        for (int i = 0; i < 8; ++i) {
            int lin = i*1024 + tid*4;
            int kl = lin >> 7, n0 = lin & 127;
            int ch = bb*HID + kc*64 + kl;
            uint2 u = *(const uint2*)&h3[(size_t)ch * THW + pos0 + n0];
            ushort_t* d = &Bs[kl*136 + ((n0 + 16*((kl>>3)&7)) & 127)];
            d[0] = (ushort_t)(u.x & 0xffffu);
            d[1] = (ushort_t)(u.x >> 16);
            d[2] = (ushort_t)(u.y & 0xffffu);
            d[3] = (ushort_t)(u.y >> 16);
        }
        __syncthreads();

        #pragma unroll
        for (int ks = 0; ks < 2; ++ks) {
            int kg = kc*2 + ks;
            bf16x8 af[4];
            #pragma unroll
            for (int ot = 0; ot < 4; ++ot)
                af[ot] = *(const bf16x8*)&g_wpackse[bb*16384 + ((kg*4+ot)<<9) + lane*8];
            bf16x8 bfr[2];
            #pragma unroll
            for (int nt = 0; nt < 2; ++nt) {
                union { short s[8]; bf16x8 v; } bu;
                #pragma unroll
                for (int j = 0; j < 8; ++j) {
                    int kl = ks*32 + q*8 + j;
                    int nn = (wv*32 + nt*16 + ln + 16*((kl>>3)&7)) & 127;
                    bu.s[j] = (short)Bs[kl*136 + nn];
                }
                bfr[nt] = bu.v;
            }
            #pragma unroll
            for (int ot = 0; ot < 4; ++ot)
                #pragma unroll
                for (int nt = 0; nt < 2; ++nt)
                    acc[ot][nt] = __builtin_amdgcn_mfma_f32_16x16x32_bf16(
                        af[ot], bfr[nt], acc[ot][nt], 0, 0, 0);
        }
        __syncthreads();
    }

    #pragma unroll
    for (int ot = 0; ot < 4; ++ot)
        #pragma unroll
        for (int nt = 0; nt < 2; ++nt)
            #pragma unroll
            for (int r = 0; r < 4; ++r) {
                int o = ot*16 + q*4 + r;
                int n = wv*32 + nt*16 + ln;
                proj[((size_t)bb*COUT + o)*THW + pos0 + n] = f2bf(acc[ot][nt][r]);
            }
}

// ------------ final fused: proj stats + norm + shortcut + maxpool (bf16 in) ---
__global__ __launch_bounds__(1024) void k_final(const ushort_t* __restrict__ proj,
                                                const float* __restrict__ x,
                                                float* __restrict__ out, int b0) {
    const int bo  = blockIdx.x;
    const int tid = threadIdx.x;
    const ushort_t* p = proj + (size_t)bo * THW;

    float s = 0.f, ss = 0.f;
    #pragma unroll
    for (int i = 0; i < THW/(1024*8); ++i) {       // 8 iters, 8 bf16/thread/iter
        uint4 u = *(const uint4*)(p + i*8192 + tid*8);
        uint_t w[4] = {u.x, u.y, u.z, u.w};
        #pragma unroll
        for (int j = 0; j < 4; ++j) {
            float f0 = __uint_as_float(w[j] << 16);
            float f1 = __uint_as_float(w[j] & 0xffff0000u);
            s += f0 + f1;
            ss = fmaf(f0, f0, fmaf(f1, f1, ss));
        }
    }
    #pragma unroll
    for (int off = 32; off > 0; off >>= 1) {
        s  += __shfl_down(s,  off, 64);
        ss += __shfl_down(ss, off, 64);
    }
    __shared__ float ls[16], lss[16];
    __shared__ float sa, sb;
    int wid = tid >> 6, lane = tid & 63;
    if (lane == 0) { ls[wid] = s; lss[wid] = ss; }
    __syncthreads();
    if (tid == 0) {
        float st = 0.f, sst = 0.f;
        #pragma unroll
        for (int i = 0; i < 16; ++i) { st += ls[i]; sst += lss[i]; }
        float m = st * (1.f/THW);
        float v = sst * (1.f/THW) - m*m;
        float is = 1.f / sqrtf(v + EPS);
        sa = is; sb = -m * is;
    }
    __syncthreads();
    const float a = sa, bb = sb;

    const size_t gbase = (size_t)(b0*COUT + bo) * THW;
    float* op = out + (size_t)(b0*COUT + bo) * (T_*1024);
    #pragma unroll
    for (int i = 0; i < 16; ++i) {
        int idx = i*1024 + tid;
        int xx = idx & 31, yy = (idx >> 5) & 31, t = idx >> 10;
        float m = -3.4e38f;
        #pragma unroll
        for (int r = 0; r < 2; ++r) {
            size_t off = (size_t)t*HW_ + (size_t)(2*yy + r)*W_ + 2*xx;
            uint_t pu = *(const uint_t*)(p + off);   // 2 bf16
            float2 x2 = *(const float2*)(x + gbase + off);
            float v0 = fmaf(__uint_as_float(pu << 16),         a, bb) + x2.x;
            float v1 = fmaf(__uint_as_float(pu & 0xffff0000u), a, bb) + x2.y;
            m = fmaxf(m, fmaxf(v0, v1));
        }
        op[idx] = m;
    }
}

extern "C" void kernel_launch(void* const* d_in, const int* in_sizes, int n_in,
                              void* d_out, int out_size, void* d_ws, size_t ws_size,
                              hipStream_t stream) {
    const float* x     = (const float*)d_in[0];
    const float* w1    = (const float*)d_in[1];
    const float* wdws  = (const float*)d_in[2];
    const float* wdwt  = (const float*)d_in[3];
    const float* wse1  = (const float*)d_in[4];
    const float* wse2  = (const float*)d_in[5];
    const float* wproj = (const float*)d_in[6];
    float* out = (float*)d_out;

    const size_t perb = 2ull * HID * THW * sizeof(ushort_t);   // 64 MB
    int nb = (ws_size >= 4*perb) ? 4 : (ws_size >= 2*perb) ? 2 : 1;

    k_prep<<<64, 256, 0, stream>>>(w1, wproj);

    for (int b0 = 0; b0 < B_; b0 += nb) {
        char* ws = (char*)d_ws;
        ushort_t* h1   = (ushort_t*)ws;
        ushort_t* h3   = h1;                                   // in-place per channel
        ushort_t* proj = (ushort_t*)(ws + (size_t)nb * HID*THW*2);

        k_expand<<<dim3(THW/64, nb), 256, 0, stream>>>(x, h1, b0);
        k_red   <<<dim3(16, nb), 256, 0, stream>>>();
        k_mid   <<<dim3(224, nb), 1024, 0, stream>>>(h1, wdws, wdwt, h3);
        k_semlp <<<nb, 256, 0, stream>>>(wse1, wse2);
        k_proj  <<<dim3(THW/128, nb), 256, 0, stream>>>(h3, proj);
        k_final <<<nb*COUT, 1024, 0, stream>>>(proj, x, out, b0);
    }
}